// Round 1
// baseline (519.129 us; speedup 1.0000x reference)
//
#include <hip/hip_runtime.h>
#include <hip/hip_bf16.h>

typedef __attribute__((ext_vector_type(8))) short bf16x8;
typedef __attribute__((ext_vector_type(4))) float f32x4;

typedef __attribute__((address_space(3))) void LdsVoid;
typedef const __attribute__((address_space(1))) void GblVoid;

__device__ __forceinline__ void gload16(const void* g, void* l) {
  __builtin_amdgcn_global_load_lds((GblVoid*)g, (LdsVoid*)l, 16, 0, 0);
}

__device__ __forceinline__ unsigned short f2bf(float f) {
  union { float f; unsigned int u; } x; x.f = f;
  unsigned int r = (x.u + 0x7fffu + ((x.u >> 16) & 1u)) >> 16;
  return (unsigned short)r;
}

// ---------------------------------------------------------------- weights prep
// Layout in ws (ushort elems): qkv_wt[768][256] @0, proj_wt[256][256] @196608,
// fc1_wt[1024][256] @262144, fc2_wt[256][1024] @524288. Total 786432 elems.
__global__ __launch_bounds__(256) void prep_w(
    const float* __restrict__ qw, const float* __restrict__ pw,
    const float* __restrict__ f1, const float* __restrict__ f2,
    unsigned short* __restrict__ out) {
  int idx = blockIdx.x * 256 + threadIdx.x;
  if (idx < 196608) { int n = idx >> 8, k = idx & 255; out[idx] = f2bf(qw[k * 768 + n]); return; }
  int i2 = idx - 196608;
  if (i2 < 65536) { int n = i2 >> 8, k = i2 & 255; out[idx] = f2bf(pw[k * 256 + n]); return; }
  int i3 = i2 - 65536;
  if (i3 < 262144) { int n = i3 >> 8, k = i3 & 255; out[idx] = f2bf(f1[k * 1024 + n]); return; }
  int i4 = i3 - 262144;
  { int n = i4 >> 10, k = i4 & 1023; out[idx] = f2bf(f2[k * 256 + n]); }
}

// ---------------------------------------------------------------- LN1 + window permute
// 4 tokens per block (1 wave per token). Output row = window-partitioned order.
__global__ __launch_bounds__(256) void ln1_kernel(
    const float* __restrict__ x, const float* __restrict__ g, const float* __restrict__ b,
    unsigned short* __restrict__ xn) {
  int lane = threadIdx.x & 63, wid = threadIdx.x >> 6;
  size_t t = (size_t)blockIdx.x * 4 + wid;
  float4 v = ((const float4*)(x + t * 256))[lane];
  float s = v.x + v.y + v.z + v.w;
  #pragma unroll
  for (int m = 1; m < 64; m <<= 1) s += __shfl_xor(s, m);
  float mean = s * (1.0f / 256.0f);
  float dx = v.x - mean, dy = v.y - mean, dz = v.z - mean, dw = v.w - mean;
  float q = dx * dx + dy * dy + dz * dz + dw * dw;
  #pragma unroll
  for (int m = 1; m < 64; m <<= 1) q += __shfl_xor(q, m);
  float rstd = rsqrtf(q * (1.0f / 256.0f) + 1e-5f);
  float4 gg = ((const float4*)g)[lane];
  float4 bb = ((const float4*)b)[lane];
  unsigned int o0 = f2bf(dx * rstd * gg.x + bb.x) | ((unsigned int)f2bf(dy * rstd * gg.y + bb.y) << 16);
  unsigned int o1 = f2bf(dz * rstd * gg.z + bb.z) | ((unsigned int)f2bf(dw * rstd * gg.w + bb.w) << 16);
  int bI = (int)(t >> 12), rem = (int)t & 4095, y = rem >> 6, xc = rem & 63;
  size_t r = ((size_t)(bI * 64 + (y >> 3) * 8 + (xc >> 3))) * 64 + (y & 7) * 8 + (xc & 7);
  uint2 o; o.x = o0; o.y = o1;
  ((uint2*)(xn + r * 256))[lane] = o;
}

// ---------------------------------------------------------------- GEMM (m97 structure)
// C[M,N] = A[M,K](bf16,rowmajor) x Bt[N,K](bf16,rowmajor == B^T).
// 128x128 tile, BK=32, 256 thr = 4 waves in 2x2, each wave 64x64 (4x4 MFMA tiles).
// EPI: 0 = bf16 out; 1 = bf16(gelu(acc+bias)); 2 = f32(acc+bias); 3 = f32 out += acc+bias
template <int EPI>
__global__ __launch_bounds__(256) void gemm_bt(
    const unsigned short* __restrict__ A, const unsigned short* __restrict__ Bt,
    unsigned short* __restrict__ outb, float* __restrict__ outf,
    const float* __restrict__ bias, int M, int N, int K) {
  __shared__ __align__(16) unsigned short lds_a[128 * 32];
  __shared__ __align__(16) unsigned short lds_b[128 * 32];
  const int tid = threadIdx.x;
  const int lane = tid & 63, wid = tid >> 6;
  const int cl = lane & 15, cg = lane >> 4;
  const size_t m0 = (size_t)blockIdx.y * 128;
  const size_t n0 = (size_t)blockIdx.x * 128;
  const int wr = wid >> 1, wc = wid & 1;
  f32x4 acc[4][4] = {};

  const unsigned short* aptr = A + (m0 + (tid >> 2)) * K + (tid & 3) * 8;
  const unsigned short* bptr = Bt + (n0 + (tid >> 2)) * K + (tid & 3) * 8;
  unsigned short* la = lds_a + wid * 512;
  unsigned short* lb = lds_b + wid * 512;
  const size_t astep = (size_t)64 * K;

  for (int k0 = 0; k0 < K; k0 += 32) {
    __syncthreads();
    gload16(aptr + k0, la);
    gload16(aptr + astep + k0, la + 2048);
    gload16(bptr + k0, lb);
    gload16(bptr + astep + k0, lb + 2048);
    __syncthreads();
    bf16x8 af[4], bfr[4];
    const unsigned short* pa = lds_a + (wr * 64 + cl) * 32 + cg * 8;
    const unsigned short* pb = lds_b + (wc * 64 + cl) * 32 + cg * 8;
    #pragma unroll
    for (int i = 0; i < 4; ++i) af[i] = *(const bf16x8*)(pa + i * 512);
    #pragma unroll
    for (int i = 0; i < 4; ++i) bfr[i] = *(const bf16x8*)(pb + i * 512);
    #pragma unroll
    for (int mi = 0; mi < 4; ++mi)
      #pragma unroll
      for (int ni = 0; ni < 4; ++ni)
        acc[mi][ni] = __builtin_amdgcn_mfma_f32_16x16x32_bf16(af[mi], bfr[ni], acc[mi][ni], 0, 0, 0);
  }

  #pragma unroll
  for (int mi = 0; mi < 4; ++mi) {
    #pragma unroll
    for (int ni = 0; ni < 4; ++ni) {
      #pragma unroll
      for (int r = 0; r < 4; ++r) {
        size_t row = m0 + wr * 64 + mi * 16 + cg * 4 + r;
        size_t col = n0 + wc * 64 + ni * 16 + cl;
        float v = acc[mi][ni][r];
        if (EPI == 0) {
          outb[row * N + col] = f2bf(v);
        } else if (EPI == 1) {
          float t = v + bias[col];
          outb[row * N + col] = f2bf(0.5f * t * (1.0f + erff(t * 0.70710678118654752f)));
        } else if (EPI == 2) {
          outf[row * N + col] = v + bias[col];
        } else {
          outf[row * N + col] += v + bias[col];
        }
      }
    }
  }
}

// ---------------------------------------------------------------- window attention
// 1 block per window (64 tokens). 4 waves; wave w handles heads w and w+4.
// qkv rows are window-ordered: row = wi*64 + n, cols [q(256)|k(256)|v(256)].
__global__ __launch_bounds__(256) void attn_win(
    const unsigned short* __restrict__ qkv, const float* __restrict__ table,
    unsigned short* __restrict__ out) {
  __shared__ float tbl[1800];
  __shared__ __align__(16) unsigned short p_lds[4][64 * 72];
  __shared__ __align__(16) unsigned short vt_lds[4][32 * 72];
  const int tid = threadIdx.x, lane = tid & 63, wid = tid >> 6;
  const int cl = lane & 15, cg = lane >> 4;
  for (int i = tid; i < 1800; i += 256) tbl[i] = table[i];
  __syncthreads();
  const size_t wbase = (size_t)blockIdx.x * 64;
  unsigned short* P = p_lds[wid];
  unsigned short* VT = vt_lds[wid];
  const float scale = 0.17677669529663687f;

  for (int hh = 0; hh < 2; ++hh) {
    const int h = wid + hh * 4;
    const int qoff = h * 32, koff = 256 + h * 32, voff = 512 + h * 32;
    // q (A-frag) and k (B-frag) load directly: lane holds row cl, k-chunk cg*8..+8
    bf16x8 qf[4], kf[4];
    #pragma unroll
    for (int mi = 0; mi < 4; ++mi)
      qf[mi] = *(const bf16x8*)&qkv[(wbase + mi * 16 + cl) * 768 + qoff + cg * 8];
    #pragma unroll
    for (int nj = 0; nj < 4; ++nj)
      kf[nj] = *(const bf16x8*)&qkv[(wbase + nj * 16 + cl) * 768 + koff + cg * 8];
    f32x4 S[4][4] = {};
    #pragma unroll
    for (int mi = 0; mi < 4; ++mi)
      #pragma unroll
      for (int nj = 0; nj < 4; ++nj)
        S[mi][nj] = __builtin_amdgcn_mfma_f32_16x16x32_bf16(qf[mi], kf[nj], S[mi][nj], 0, 0, 0);

    // stage V^T : VT[d][j] = V[j][d]; lane owns token j = lane
    {
      const unsigned short* vrow = &qkv[(wbase + lane) * 768 + voff];
      unsigned short tmp[32];
      #pragma unroll
      for (int p = 0; p < 4; ++p) *(uint4*)&tmp[p * 8] = ((const uint4*)vrow)[p];
      #pragma unroll
      for (int d = 0; d < 32; ++d) VT[d * 72 + lane] = tmp[d];
    }

    // softmax (bias added on the fly); keep 1/rowsum for post-PV scaling
    float rs[4][4];
    #pragma unroll
    for (int mi = 0; mi < 4; ++mi) {
      #pragma unroll
      for (int r = 0; r < 4; ++r) {
        const int i = mi * 16 + cg * 4 + r;
        const int yi = i >> 3, xi = i & 7;
        float v[4];
        float m = -1e30f;
        #pragma unroll
        for (int nj = 0; nj < 4; ++nj) {
          const int j = nj * 16 + cl;
          const int yj = j >> 3, xj = j & 7;
          float bia = tbl[((yi - yj + 7) * 15 + (xi - xj + 7)) * 8 + h];
          v[nj] = S[mi][nj][r] * scale + bia;
          m = fmaxf(m, v[nj]);
        }
        #pragma unroll
        for (int mk = 1; mk < 16; mk <<= 1) m = fmaxf(m, __shfl_xor(m, mk));
        float s = 0.0f;
        #pragma unroll
        for (int nj = 0; nj < 4; ++nj) { v[nj] = expf(v[nj] - m); s += v[nj]; }
        #pragma unroll
        for (int mk = 1; mk < 16; mk <<= 1) s += __shfl_xor(s, mk);
        rs[mi][r] = s;
        #pragma unroll
        for (int nj = 0; nj < 4; ++nj) P[i * 72 + nj * 16 + cl] = f2bf(v[nj]);
      }
    }

    // PV: out[64x32] = P[64x64] @ V[64x32]
    f32x4 O[4][2] = {};
    #pragma unroll
    for (int ks = 0; ks < 2; ++ks) {
      bf16x8 pa[4], vb[2];
      #pragma unroll
      for (int mi = 0; mi < 4; ++mi)
        pa[mi] = *(const bf16x8*)&P[(mi * 16 + cl) * 72 + ks * 32 + cg * 8];
      #pragma unroll
      for (int nd = 0; nd < 2; ++nd)
        vb[nd] = *(const bf16x8*)&VT[(nd * 16 + cl) * 72 + ks * 32 + cg * 8];
      #pragma unroll
      for (int mi = 0; mi < 4; ++mi)
        #pragma unroll
        for (int nd = 0; nd < 2; ++nd)
          O[mi][nd] = __builtin_amdgcn_mfma_f32_16x16x32_bf16(pa[mi], vb[nd], O[mi][nd], 0, 0, 0);
    }

    #pragma unroll
    for (int mi = 0; mi < 4; ++mi)
      #pragma unroll
      for (int nd = 0; nd < 2; ++nd)
        #pragma unroll
        for (int r = 0; r < 4; ++r) {
          float val = O[mi][nd][r] / rs[mi][r];
          out[(wbase + mi * 16 + cg * 4 + r) * 256 + h * 32 + nd * 16 + cl] = f2bf(val);
        }
  }
}

// ---------------------------------------------------------------- epilogue 1
// x2 = x + attnproj(un-permuted, bias already added); write x2 -> d_out (fp32),
// h2 = LN2(x2) bf16 (original token order).
__global__ __launch_bounds__(256) void ep1_kernel(
    const float* __restrict__ x, const float* __restrict__ pout,
    const float* __restrict__ g, const float* __restrict__ b,
    float* __restrict__ x2out, unsigned short* __restrict__ h2) {
  int lane = threadIdx.x & 63, wid = threadIdx.x >> 6;
  size_t t = (size_t)blockIdx.x * 4 + wid;
  int bI = (int)(t >> 12), rem = (int)t & 4095, y = rem >> 6, xc = rem & 63;
  size_t r = ((size_t)(bI * 64 + (y >> 3) * 8 + (xc >> 3))) * 64 + (y & 7) * 8 + (xc & 7);
  float4 xv = ((const float4*)(x + t * 256))[lane];
  float4 pv = ((const float4*)(pout + r * 256))[lane];
  float4 s4; s4.x = xv.x + pv.x; s4.y = xv.y + pv.y; s4.z = xv.z + pv.z; s4.w = xv.w + pv.w;
  ((float4*)(x2out + t * 256))[lane] = s4;
  float s = s4.x + s4.y + s4.z + s4.w;
  #pragma unroll
  for (int m = 1; m < 64; m <<= 1) s += __shfl_xor(s, m);
  float mean = s * (1.0f / 256.0f);
  float dx = s4.x - mean, dy = s4.y - mean, dz = s4.z - mean, dw = s4.w - mean;
  float q = dx * dx + dy * dy + dz * dz + dw * dw;
  #pragma unroll
  for (int m = 1; m < 64; m <<= 1) q += __shfl_xor(q, m);
  float rstd = rsqrtf(q * (1.0f / 256.0f) + 1e-5f);
  float4 gg = ((const float4*)g)[lane];
  float4 bb = ((const float4*)b)[lane];
  uint2 o;
  o.x = f2bf(dx * rstd * gg.x + bb.x) | ((unsigned int)f2bf(dy * rstd * gg.y + bb.y) << 16);
  o.y = f2bf(dz * rstd * gg.z + bb.z) | ((unsigned int)f2bf(dw * rstd * gg.w + bb.w) << 16);
  ((uint2*)(h2 + t * 256))[lane] = o;
}

// ---------------------------------------------------------------- launch
extern "C" void kernel_launch(void* const* d_in, const int* in_sizes, int n_in,
                              void* d_out, int out_size, void* d_ws, size_t ws_size,
                              hipStream_t stream) {
  (void)in_sizes; (void)n_in; (void)out_size; (void)ws_size;
  const float* x       = (const float*)d_in[0];
  const float* ln1_g   = (const float*)d_in[3];
  const float* ln1_b   = (const float*)d_in[4];
  const float* qkv_w   = (const float*)d_in[5];
  const float* proj_w  = (const float*)d_in[6];
  const float* proj_b  = (const float*)d_in[7];
  const float* rel_tbl = (const float*)d_in[8];
  const float* ln2_g   = (const float*)d_in[9];
  const float* ln2_b   = (const float*)d_in[10];
  const float* fc1_w   = (const float*)d_in[11];
  const float* fc1_b   = (const float*)d_in[12];
  const float* fc2_w   = (const float*)d_in[13];
  const float* fc2_b   = (const float*)d_in[14];
  float* out = (float*)d_out;

  char* ws = (char*)d_ws;
  const size_t OFF_XN   = 1572864;                 // weights: 786432*2 B
  const size_t OFF_QKV  = OFF_XN + 33554432;       // xn/h2: 65536*256*2
  const size_t OFF_ATTN = OFF_QKV + 100663296;     // qkv: 65536*768*2
  unsigned short* Wt      = (unsigned short*)ws;
  unsigned short* xn      = (unsigned short*)(ws + OFF_XN);
  unsigned short* h2      = xn;                          // reuse after QKV GEMM
  unsigned short* qkv     = (unsigned short*)(ws + OFF_QKV);
  float*          projout = (float*)(ws + OFF_QKV);      // reuse (qkv dead after attn)
  unsigned short* fc1out  = (unsigned short*)(ws + OFF_QKV); // spans qkv+attn regions
  unsigned short* attnout = (unsigned short*)(ws + OFF_ATTN);

  prep_w<<<3072, 256, 0, stream>>>(qkv_w, proj_w, fc1_w, fc2_w, Wt);
  ln1_kernel<<<16384, 256, 0, stream>>>(x, ln1_g, ln1_b, xn);
  gemm_bt<0><<<dim3(6, 512), 256, 0, stream>>>(xn, Wt, qkv, nullptr, nullptr, 65536, 768, 256);
  attn_win<<<1024, 256, 0, stream>>>(qkv, rel_tbl, attnout);
  gemm_bt<2><<<dim3(2, 512), 256, 0, stream>>>(attnout, Wt + 196608, nullptr, projout, proj_b, 65536, 256, 256);
  ep1_kernel<<<16384, 256, 0, stream>>>(x, projout, ln2_g, ln2_b, out, h2);
  gemm_bt<1><<<dim3(8, 512), 256, 0, stream>>>(h2, Wt + 262144, fc1out, nullptr, fc1_b, 65536, 1024, 256);
  gemm_bt<3><<<dim3(2, 512), 256, 0, stream>>>(fc1out, Wt + 524288, nullptr, out, fc2_b, 65536, 256, 1024);
}

// Round 2
// 489.563 us; speedup vs baseline: 1.0604x; 1.0604x over previous
//
#include <hip/hip_runtime.h>
#include <hip/hip_bf16.h>

typedef __attribute__((ext_vector_type(8))) short bf16x8;
typedef __attribute__((ext_vector_type(4))) float f32x4;

typedef __attribute__((address_space(3))) void LdsVoid;
typedef const __attribute__((address_space(1))) void GblVoid;

__device__ __forceinline__ void gload16(const void* g, void* l) {
  __builtin_amdgcn_global_load_lds((GblVoid*)g, (LdsVoid*)l, 16, 0, 0);
}

__device__ __forceinline__ unsigned short f2bf(float f) {
  union { float f; unsigned int u; } x; x.f = f;
  unsigned int r = (x.u + 0x7fffu + ((x.u >> 16) & 1u)) >> 16;
  return (unsigned short)r;
}

// ---------------------------------------------------------------- weights prep
// Layout in ws (ushort elems): qkv_wt[768][256] @0, proj_wt[256][256] @196608,
// fc1_wt[1024][256] @262144, fc2_wt[256][1024] @524288. Total 786432 elems.
__global__ __launch_bounds__(256) void prep_w(
    const float* __restrict__ qw, const float* __restrict__ pw,
    const float* __restrict__ f1, const float* __restrict__ f2,
    unsigned short* __restrict__ out) {
  int idx = blockIdx.x * 256 + threadIdx.x;
  if (idx < 196608) { int n = idx >> 8, k = idx & 255; out[idx] = f2bf(qw[k * 768 + n]); return; }
  int i2 = idx - 196608;
  if (i2 < 65536) { int n = i2 >> 8, k = i2 & 255; out[idx] = f2bf(pw[k * 256 + n]); return; }
  int i3 = i2 - 65536;
  if (i3 < 262144) { int n = i3 >> 8, k = i3 & 255; out[idx] = f2bf(f1[k * 1024 + n]); return; }
  int i4 = i3 - 262144;
  { int n = i4 >> 10, k = i4 & 1023; out[idx] = f2bf(f2[k * 256 + n]); }
}

// ---------------------------------------------------------------- LN1 + window permute
__global__ __launch_bounds__(256) void ln1_kernel(
    const float* __restrict__ x, const float* __restrict__ g, const float* __restrict__ b,
    unsigned short* __restrict__ xn) {
  int lane = threadIdx.x & 63, wid = threadIdx.x >> 6;
  size_t t = (size_t)blockIdx.x * 4 + wid;
  float4 v = ((const float4*)(x + t * 256))[lane];
  float s = v.x + v.y + v.z + v.w;
  #pragma unroll
  for (int m = 1; m < 64; m <<= 1) s += __shfl_xor(s, m);
  float mean = s * (1.0f / 256.0f);
  float dx = v.x - mean, dy = v.y - mean, dz = v.z - mean, dw = v.w - mean;
  float q = dx * dx + dy * dy + dz * dz + dw * dw;
  #pragma unroll
  for (int m = 1; m < 64; m <<= 1) q += __shfl_xor(q, m);
  float rstd = rsqrtf(q * (1.0f / 256.0f) + 1e-5f);
  float4 gg = ((const float4*)g)[lane];
  float4 bb = ((const float4*)b)[lane];
  unsigned int o0 = f2bf(dx * rstd * gg.x + bb.x) | ((unsigned int)f2bf(dy * rstd * gg.y + bb.y) << 16);
  unsigned int o1 = f2bf(dz * rstd * gg.z + bb.z) | ((unsigned int)f2bf(dw * rstd * gg.w + bb.w) << 16);
  int bI = (int)(t >> 12), rem = (int)t & 4095, y = rem >> 6, xc = rem & 63;
  size_t r = ((size_t)(bI * 64 + (y >> 3) * 8 + (xc >> 3))) * 64 + (y & 7) * 8 + (xc & 7);
  uint2 o; o.x = o0; o.y = o1;
  ((uint2*)(xn + r * 256))[lane] = o;
}

// ---------------------------------------------------------------- GEMM (pipelined)
// C[M,N] = A[M,K](bf16,rm) x Bt[N,K](bf16,rm = B^T). 128x128 tile, BK=32,
// 4 waves 2x2. 3-buffer LDS pipeline, counted vmcnt(4), raw barriers,
// chunk-XOR swizzle (pre-swizzled global source + swizzled ds_read).
// EPI: 0 = bf16 out; 1 = bf16(gelu(acc+bias)); 2 = f32(acc+bias); 3 = f32 out += acc+bias
template <int EPI>
__global__ __launch_bounds__(256) void gemm_bt(
    const unsigned short* __restrict__ A, const unsigned short* __restrict__ Bt,
    unsigned short* __restrict__ outb, float* __restrict__ outf,
    const float* __restrict__ bias, int M, int N, int K) {
  // per buffer: A 128x32 (4096 elems) + B 128x32 (4096) = 16KB; 3 bufs = 48KB
  __shared__ __align__(16) unsigned short lds[3 * 8192];
  const int tid = threadIdx.x;
  const int lane = tid & 63, wid = tid >> 6;
  const int cl = lane & 15, cg = lane >> 4;
  const size_t m0 = (size_t)blockIdx.y * 128;
  const size_t n0 = (size_t)blockIdx.x * 128;
  const int wr = wid >> 1, wc = wid & 1;
  f32x4 acc[4][4] = {};

  // staging: thread tid covers row ra=tid>>2 (and ra+64), 8-elem chunk (tid&3),
  // source pre-swizzled: slot s in LDS holds logical chunk s^(row&3)
  const int ra = tid >> 2;
  const int sc = ((tid & 3) ^ (ra & 3)) * 8;
  const unsigned short* aptr = A + (m0 + ra) * K + sc;
  const unsigned short* bptr = Bt + (n0 + ra) * K + sc;
  const size_t astep = (size_t)64 * K;
  unsigned short* wbaseA = lds + wid * 512;         // + buf*8192
  unsigned short* wbaseB = lds + 4096 + wid * 512;  // + buf*8192

  const int nt = K >> 5;

  #define STAGE(T, B)                                            \
    {                                                            \
      const unsigned short* as_ = aptr + (T) * 32;               \
      const unsigned short* bs_ = bptr + (T) * 32;               \
      unsigned short* da_ = wbaseA + (B) * 8192;                 \
      unsigned short* db_ = wbaseB + (B) * 8192;                 \
      gload16(as_, da_); gload16(as_ + astep, da_ + 2048);       \
      gload16(bs_, db_); gload16(bs_ + astep, db_ + 2048);       \
    }

  // read-side swizzle: row%4 == cl%4 for all fragment rows
  const int rsw = (cg ^ (cl & 3)) * 8;

  #define COMPUTE(B)                                                             \
    {                                                                            \
      const unsigned short* base_ = lds + (B) * 8192;                            \
      bf16x8 af[4], bfr[4];                                                      \
      _Pragma("unroll")                                                          \
      for (int i = 0; i < 4; ++i)                                                \
        af[i] = *(const bf16x8*)(base_ + (wr * 64 + i * 16 + cl) * 32 + rsw);    \
      _Pragma("unroll")                                                          \
      for (int i = 0; i < 4; ++i)                                                \
        bfr[i] = *(const bf16x8*)(base_ + 4096 + (wc * 64 + i * 16 + cl) * 32 + rsw); \
      _Pragma("unroll")                                                          \
      for (int mi = 0; mi < 4; ++mi)                                             \
        _Pragma("unroll")                                                        \
        for (int ni = 0; ni < 4; ++ni)                                           \
          acc[mi][ni] = __builtin_amdgcn_mfma_f32_16x16x32_bf16(af[mi], bfr[ni], acc[mi][ni], 0, 0, 0); \
    }

  // prologue: tiles 0,1 in flight (8 vmem ops)
  STAGE(0, 0);
  STAGE(1, 1);
  int c0 = 0, c1 = 1, c2 = 2;
  for (int t = 0; t < nt - 1; ++t) {
    // tile t's 4 loads are the oldest; allow tile t+1's 4 to stay in flight
    asm volatile("s_waitcnt vmcnt(4)" ::: "memory");
    __builtin_amdgcn_s_barrier();
    if (t + 2 < nt) STAGE(t + 2, c2);
    COMPUTE(c0);
    int tmp = c0; c0 = c1; c1 = c2; c2 = tmp;
  }
  asm volatile("s_waitcnt vmcnt(0)" ::: "memory");
  __builtin_amdgcn_s_barrier();
  COMPUTE(c0);
  #undef STAGE
  #undef COMPUTE

  #pragma unroll
  for (int mi = 0; mi < 4; ++mi) {
    #pragma unroll
    for (int ni = 0; ni < 4; ++ni) {
      #pragma unroll
      for (int r = 0; r < 4; ++r) {
        size_t row = m0 + wr * 64 + mi * 16 + cg * 4 + r;
        size_t col = n0 + wc * 64 + ni * 16 + cl;
        float v = acc[mi][ni][r];
        if (EPI == 0) {
          outb[row * N + col] = f2bf(v);
        } else if (EPI == 1) {
          float t = v + bias[col];
          outb[row * N + col] = f2bf(0.5f * t * (1.0f + erff(t * 0.70710678118654752f)));
        } else if (EPI == 2) {
          outf[row * N + col] = v + bias[col];
        } else {
          outf[row * N + col] += v + bias[col];
        }
      }
    }
  }
}

// ---------------------------------------------------------------- window attention
__global__ __launch_bounds__(256) void attn_win(
    const unsigned short* __restrict__ qkv, const float* __restrict__ table,
    unsigned short* __restrict__ out) {
  __shared__ float tbl[1800];
  __shared__ __align__(16) unsigned short p_lds[4][64 * 72];
  __shared__ __align__(16) unsigned short vt_lds[4][32 * 72];
  const int tid = threadIdx.x, lane = tid & 63, wid = tid >> 6;
  const int cl = lane & 15, cg = lane >> 4;
  for (int i = tid; i < 1800; i += 256) tbl[i] = table[i];
  __syncthreads();
  const size_t wbase = (size_t)blockIdx.x * 64;
  unsigned short* P = p_lds[wid];
  unsigned short* VT = vt_lds[wid];
  const float scale = 0.17677669529663687f;

  for (int hh = 0; hh < 2; ++hh) {
    const int h = wid + hh * 4;
    const int qoff = h * 32, koff = 256 + h * 32, voff = 512 + h * 32;
    bf16x8 qf[4], kf[4];
    #pragma unroll
    for (int mi = 0; mi < 4; ++mi)
      qf[mi] = *(const bf16x8*)&qkv[(wbase + mi * 16 + cl) * 768 + qoff + cg * 8];
    #pragma unroll
    for (int nj = 0; nj < 4; ++nj)
      kf[nj] = *(const bf16x8*)&qkv[(wbase + nj * 16 + cl) * 768 + koff + cg * 8];
    f32x4 S[4][4] = {};
    #pragma unroll
    for (int mi = 0; mi < 4; ++mi)
      #pragma unroll
      for (int nj = 0; nj < 4; ++nj)
        S[mi][nj] = __builtin_amdgcn_mfma_f32_16x16x32_bf16(qf[mi], kf[nj], S[mi][nj], 0, 0, 0);

    {
      const unsigned short* vrow = &qkv[(wbase + lane) * 768 + voff];
      unsigned short tmp[32];
      #pragma unroll
      for (int p = 0; p < 4; ++p) *(uint4*)&tmp[p * 8] = ((const uint4*)vrow)[p];
      #pragma unroll
      for (int d = 0; d < 32; ++d) VT[d * 72 + lane] = tmp[d];
    }

    float rs[4][4];
    #pragma unroll
    for (int mi = 0; mi < 4; ++mi) {
      #pragma unroll
      for (int r = 0; r < 4; ++r) {
        const int i = mi * 16 + cg * 4 + r;
        const int yi = i >> 3, xi = i & 7;
        float v[4];
        float m = -1e30f;
        #pragma unroll
        for (int nj = 0; nj < 4; ++nj) {
          const int j = nj * 16 + cl;
          const int yj = j >> 3, xj = j & 7;
          float bia = tbl[((yi - yj + 7) * 15 + (xi - xj + 7)) * 8 + h];
          v[nj] = S[mi][nj][r] * scale + bia;
          m = fmaxf(m, v[nj]);
        }
        #pragma unroll
        for (int mk = 1; mk < 16; mk <<= 1) m = fmaxf(m, __shfl_xor(m, mk));
        float s = 0.0f;
        #pragma unroll
        for (int nj = 0; nj < 4; ++nj) { v[nj] = expf(v[nj] - m); s += v[nj]; }
        #pragma unroll
        for (int mk = 1; mk < 16; mk <<= 1) s += __shfl_xor(s, mk);
        rs[mi][r] = s;
        #pragma unroll
        for (int nj = 0; nj < 4; ++nj) P[i * 72 + nj * 16 + cl] = f2bf(v[nj]);
      }
    }

    f32x4 O[4][2] = {};
    #pragma unroll
    for (int ks = 0; ks < 2; ++ks) {
      bf16x8 pa[4], vb[2];
      #pragma unroll
      for (int mi = 0; mi < 4; ++mi)
        pa[mi] = *(const bf16x8*)&P[(mi * 16 + cl) * 72 + ks * 32 + cg * 8];
      #pragma unroll
      for (int nd = 0; nd < 2; ++nd)
        vb[nd] = *(const bf16x8*)&VT[(nd * 16 + cl) * 72 + ks * 32 + cg * 8];
      #pragma unroll
      for (int mi = 0; mi < 4; ++mi)
        #pragma unroll
        for (int nd = 0; nd < 2; ++nd)
          O[mi][nd] = __builtin_amdgcn_mfma_f32_16x16x32_bf16(pa[mi], vb[nd], O[mi][nd], 0, 0, 0);
    }

    #pragma unroll
    for (int mi = 0; mi < 4; ++mi)
      #pragma unroll
      for (int nd = 0; nd < 2; ++nd)
        #pragma unroll
        for (int r = 0; r < 4; ++r) {
          float val = O[mi][nd][r] / rs[mi][r];
          out[(wbase + mi * 16 + cg * 4 + r) * 256 + h * 32 + nd * 16 + cl] = f2bf(val);
        }
  }
}

// ---------------------------------------------------------------- epilogue 1
__global__ __launch_bounds__(256) void ep1_kernel(
    const float* __restrict__ x, const float* __restrict__ pout,
    const float* __restrict__ g, const float* __restrict__ b,
    float* __restrict__ x2out, unsigned short* __restrict__ h2) {
  int lane = threadIdx.x & 63, wid = threadIdx.x >> 6;
  size_t t = (size_t)blockIdx.x * 4 + wid;
  int bI = (int)(t >> 12), rem = (int)t & 4095, y = rem >> 6, xc = rem & 63;
  size_t r = ((size_t)(bI * 64 + (y >> 3) * 8 + (xc >> 3))) * 64 + (y & 7) * 8 + (xc & 7);
  float4 xv = ((const float4*)(x + t * 256))[lane];
  float4 pv = ((const float4*)(pout + r * 256))[lane];
  float4 s4; s4.x = xv.x + pv.x; s4.y = xv.y + pv.y; s4.z = xv.z + pv.z; s4.w = xv.w + pv.w;
  ((float4*)(x2out + t * 256))[lane] = s4;
  float s = s4.x + s4.y + s4.z + s4.w;
  #pragma unroll
  for (int m = 1; m < 64; m <<= 1) s += __shfl_xor(s, m);
  float mean = s * (1.0f / 256.0f);
  float dx = s4.x - mean, dy = s4.y - mean, dz = s4.z - mean, dw = s4.w - mean;
  float q = dx * dx + dy * dy + dz * dz + dw * dw;
  #pragma unroll
  for (int m = 1; m < 64; m <<= 1) q += __shfl_xor(q, m);
  float rstd = rsqrtf(q * (1.0f / 256.0f) + 1e-5f);
  float4 gg = ((const float4*)g)[lane];
  float4 bb = ((const float4*)b)[lane];
  uint2 o;
  o.x = f2bf(dx * rstd * gg.x + bb.x) | ((unsigned int)f2bf(dy * rstd * gg.y + bb.y) << 16);
  o.y = f2bf(dz * rstd * gg.z + bb.z) | ((unsigned int)f2bf(dw * rstd * gg.w + bb.w) << 16);
  ((uint2*)(h2 + t * 256))[lane] = o;
}

// ---------------------------------------------------------------- launch
extern "C" void kernel_launch(void* const* d_in, const int* in_sizes, int n_in,
                              void* d_out, int out_size, void* d_ws, size_t ws_size,
                              hipStream_t stream) {
  (void)in_sizes; (void)n_in; (void)out_size; (void)ws_size;
  const float* x       = (const float*)d_in[0];
  const float* ln1_g   = (const float*)d_in[3];
  const float* ln1_b   = (const float*)d_in[4];
  const float* qkv_w   = (const float*)d_in[5];
  const float* proj_w  = (const float*)d_in[6];
  const float* proj_b  = (const float*)d_in[7];
  const float* rel_tbl = (const float*)d_in[8];
  const float* ln2_g   = (const float*)d_in[9];
  const float* ln2_b   = (const float*)d_in[10];
  const float* fc1_w   = (const float*)d_in[11];
  const float* fc1_b   = (const float*)d_in[12];
  const float* fc2_w   = (const float*)d_in[13];
  const float* fc2_b   = (const float*)d_in[14];
  float* out = (float*)d_out;

  char* ws = (char*)d_ws;
  const size_t OFF_XN   = 1572864;                 // weights: 786432*2 B
  const size_t OFF_QKV  = OFF_XN + 33554432;       // xn/h2: 65536*256*2
  const size_t OFF_ATTN = OFF_QKV + 100663296;     // qkv: 65536*768*2
  unsigned short* Wt      = (unsigned short*)ws;
  unsigned short* xn      = (unsigned short*)(ws + OFF_XN);
  unsigned short* h2      = xn;                          // reuse after QKV GEMM
  unsigned short* qkv     = (unsigned short*)(ws + OFF_QKV);
  float*          projout = (float*)(ws + OFF_QKV);      // reuse (qkv dead after attn)
  unsigned short* fc1out  = (unsigned short*)(ws + OFF_QKV); // spans qkv+attn regions
  unsigned short* attnout = (unsigned short*)(ws + OFF_ATTN);

  prep_w<<<3072, 256, 0, stream>>>(qkv_w, proj_w, fc1_w, fc2_w, Wt);
  ln1_kernel<<<16384, 256, 0, stream>>>(x, ln1_g, ln1_b, xn);
  gemm_bt<0><<<dim3(6, 512), 256, 0, stream>>>(xn, Wt, qkv, nullptr, nullptr, 65536, 768, 256);
  attn_win<<<1024, 256, 0, stream>>>(qkv, rel_tbl, attnout);
  gemm_bt<2><<<dim3(2, 512), 256, 0, stream>>>(attnout, Wt + 196608, nullptr, projout, proj_b, 65536, 256, 256);
  ep1_kernel<<<16384, 256, 0, stream>>>(x, projout, ln2_g, ln2_b, out, h2);
  gemm_bt<1><<<dim3(8, 512), 256, 0, stream>>>(h2, Wt + 262144, fc1out, nullptr, fc1_b, 65536, 1024, 256);
  gemm_bt<3><<<dim3(2, 512), 256, 0, stream>>>(fc1out, Wt + 524288, nullptr, out, fc2_b, 65536, 256, 1024);
}

// Round 3
// 455.343 us; speedup vs baseline: 1.1401x; 1.0752x over previous
//
#include <hip/hip_runtime.h>
#include <hip/hip_bf16.h>

typedef __attribute__((ext_vector_type(8))) short bf16x8;
typedef __attribute__((ext_vector_type(4))) float f32x4;

typedef __attribute__((address_space(3))) void LdsVoid;
typedef const __attribute__((address_space(1))) void GblVoid;

__device__ __forceinline__ void gload16(const void* g, void* l) {
  __builtin_amdgcn_global_load_lds((GblVoid*)g, (LdsVoid*)l, 16, 0, 0);
}

__device__ __forceinline__ unsigned short f2bf(float f) {
  union { float f; unsigned int u; } x; x.f = f;
  unsigned int r = (x.u + 0x7fffu + ((x.u >> 16) & 1u)) >> 16;
  return (unsigned short)r;
}

// ---------------------------------------------------------------- weights prep
// Layout in ws (ushort elems): qkv_wt[768][256] @0, proj_wt[256][256] @196608,
// fc1_wt[1024][256] @262144, fc2_wt[256][1024] @524288. Total 786432 elems.
__global__ __launch_bounds__(256) void prep_w(
    const float* __restrict__ qw, const float* __restrict__ pw,
    const float* __restrict__ f1, const float* __restrict__ f2,
    unsigned short* __restrict__ out) {
  int idx = blockIdx.x * 256 + threadIdx.x;
  if (idx < 196608) { int n = idx >> 8, k = idx & 255; out[idx] = f2bf(qw[k * 768 + n]); return; }
  int i2 = idx - 196608;
  if (i2 < 65536) { int n = i2 >> 8, k = i2 & 255; out[idx] = f2bf(pw[k * 256 + n]); return; }
  int i3 = i2 - 65536;
  if (i3 < 262144) { int n = i3 >> 8, k = i3 & 255; out[idx] = f2bf(f1[k * 1024 + n]); return; }
  int i4 = i3 - 262144;
  { int n = i4 >> 10, k = i4 & 1023; out[idx] = f2bf(f2[k * 256 + n]); }
}

// ---------------------------------------------------------------- LN1 + window permute
__global__ __launch_bounds__(256) void ln1_kernel(
    const float* __restrict__ x, const float* __restrict__ g, const float* __restrict__ b,
    unsigned short* __restrict__ xn) {
  int lane = threadIdx.x & 63, wid = threadIdx.x >> 6;
  size_t t = (size_t)blockIdx.x * 4 + wid;
  float4 v = ((const float4*)(x + t * 256))[lane];
  float s = v.x + v.y + v.z + v.w;
  #pragma unroll
  for (int m = 1; m < 64; m <<= 1) s += __shfl_xor(s, m);
  float mean = s * (1.0f / 256.0f);
  float dx = v.x - mean, dy = v.y - mean, dz = v.z - mean, dw = v.w - mean;
  float q = dx * dx + dy * dy + dz * dz + dw * dw;
  #pragma unroll
  for (int m = 1; m < 64; m <<= 1) q += __shfl_xor(q, m);
  float rstd = rsqrtf(q * (1.0f / 256.0f) + 1e-5f);
  float4 gg = ((const float4*)g)[lane];
  float4 bb = ((const float4*)b)[lane];
  unsigned int o0 = f2bf(dx * rstd * gg.x + bb.x) | ((unsigned int)f2bf(dy * rstd * gg.y + bb.y) << 16);
  unsigned int o1 = f2bf(dz * rstd * gg.z + bb.z) | ((unsigned int)f2bf(dw * rstd * gg.w + bb.w) << 16);
  int bI = (int)(t >> 12), rem = (int)t & 4095, y = rem >> 6, xc = rem & 63;
  size_t r = ((size_t)(bI * 64 + (y >> 3) * 8 + (xc >> 3))) * 64 + (y & 7) * 8 + (xc & 7);
  uint2 o; o.x = o0; o.y = o1;
  ((uint2*)(xn + r * 256))[lane] = o;
}

// ---------------------------------------------------------------- GEMM (BK=64, 2-buf, counted vmcnt)
// C[M,N] = A[M,K](bf16,rm) x Bt[N,K](bf16,rm = B^T). 128x128 tile, BK=64,
// 4 waves 2x2, 2-buffer LDS (64KB), 2 tiles in flight (128B/row granules),
// chunk-XOR swizzle (pre-swizzled global source + swizzled ds_read),
// XCD chunk swizzle (all grids have nwg % 8 == 0).
// EPI: 0 = bf16 out; 1 = bf16(gelu(acc+bias)); 3 = f32 out += acc+bias;
//      4 = f32 out[unpermute(row)] = acc + bias + xres[unpermute(row)]
template <int EPI>
__global__ __launch_bounds__(256) void gemm_bt(
    const unsigned short* __restrict__ A, const unsigned short* __restrict__ Bt,
    unsigned short* __restrict__ outb, float* __restrict__ outf,
    const float* __restrict__ bias, const float* __restrict__ xres,
    int M, int N, int K) {
  __shared__ __align__(16) unsigned short lds[2 * 16384];  // 64KB
  const int tid = threadIdx.x;
  const int lane = tid & 63, wid = tid >> 6;
  const int cl = lane & 15, cg = lane >> 4;
  // XCD chunk swizzle: chunks of nwg/8 consecutive virtual ids per XCD
  const unsigned nwg = gridDim.x * gridDim.y;
  const unsigned orig = blockIdx.y * gridDim.x + blockIdx.x;
  const unsigned virt = (orig & 7) * (nwg >> 3) + (orig >> 3);
  const unsigned bx = virt % gridDim.x, by = virt / gridDim.x;
  const size_t m0 = (size_t)by * 128;
  const size_t n0 = (size_t)bx * 128;
  const int wr = wid >> 1, wc = wid & 1;
  f32x4 acc[4][4] = {};

  // staging: wave w covers rows w*32..w*32+32 of both A and B tiles.
  // instr j covers 8 rows; lane l -> row base+ (l>>3), 16B slot (l&7).
  // pre-swizzled source: LDS slot s of row r holds logical chunk s^(r&7).
  const int r8 = lane >> 3;
  const int gsw = ((lane & 7) ^ r8) * 8;  // elems
  const unsigned short* aStage = A + (m0 + wid * 32 + r8) * K + gsw;
  const unsigned short* bStage = Bt + (n0 + wid * 32 + r8) * K + gsw;
  const size_t jstep = (size_t)8 * K;
  const int nt = K >> 6;

  #define STAGE(T, B)                                                   \
    { const int ko_ = (T) * 64;                                         \
      unsigned short* la_ = lds + (B) * 16384 + wid * 2048;             \
      unsigned short* lb_ = la_ + 8192;                                 \
      _Pragma("unroll")                                                 \
      for (int j = 0; j < 4; ++j) {                                     \
        gload16(aStage + ko_ + j * jstep, la_ + j * 512);               \
        gload16(bStage + ko_ + j * jstep, lb_ + j * 512);               \
      } }

  bf16x8 af[2][4], bfr[2][4];
  #define READF(B)                                                          \
    { const unsigned short* base_ = lds + (B) * 16384;                      \
      _Pragma("unroll")                                                     \
      for (int kk = 0; kk < 2; ++kk)                                        \
        _Pragma("unroll")                                                   \
        for (int i = 0; i < 4; ++i) {                                       \
          const int sl_ = ((kk * 4 + cg) ^ (cl & 7)) * 8;                   \
          af[kk][i]  = *(const bf16x8*)(base_ + (wr * 64 + i * 16 + cl) * 64 + sl_);        \
          bfr[kk][i] = *(const bf16x8*)(base_ + 8192 + (wc * 64 + i * 16 + cl) * 64 + sl_); \
        } }

  #define MFMAS()                                                           \
    { _Pragma("unroll")                                                     \
      for (int kk = 0; kk < 2; ++kk)                                        \
        _Pragma("unroll")                                                   \
        for (int mi = 0; mi < 4; ++mi)                                      \
          _Pragma("unroll")                                                 \
          for (int ni = 0; ni < 4; ++ni)                                    \
            acc[mi][ni] = __builtin_amdgcn_mfma_f32_16x16x32_bf16(af[kk][mi], bfr[kk][ni], acc[mi][ni], 0, 0, 0); }

  STAGE(0, 0);
  STAGE(1, 1);
  for (int t = 0; t < nt; ++t) {
    if (t == nt - 1) { asm volatile("s_waitcnt vmcnt(0)" ::: "memory"); }
    else             { asm volatile("s_waitcnt vmcnt(8)" ::: "memory"); }
    __builtin_amdgcn_s_barrier();           // tile t visible to all waves
    READF(t & 1);
    __builtin_amdgcn_sched_barrier(0);
    asm volatile("s_waitcnt lgkmcnt(0)" ::: "memory");  // my reads of buf done
    __builtin_amdgcn_s_barrier();           // all waves done reading buf
    __builtin_amdgcn_sched_barrier(0);
    if (t + 2 < nt) STAGE(t + 2, t & 1);    // overwrite freed buffer
    MFMAS();
  }
  #undef STAGE
  #undef READF
  #undef MFMAS

  #pragma unroll
  for (int mi = 0; mi < 4; ++mi) {
    #pragma unroll
    for (int ni = 0; ni < 4; ++ni) {
      #pragma unroll
      for (int r = 0; r < 4; ++r) {
        size_t row = m0 + wr * 64 + mi * 16 + cg * 4 + r;
        size_t col = n0 + wc * 64 + ni * 16 + cl;
        float v = acc[mi][ni][r];
        if (EPI == 0) {
          outb[row * N + col] = f2bf(v);
        } else if (EPI == 1) {
          float t = v + bias[col];
          outb[row * N + col] = f2bf(0.5f * t * (1.0f + erff(t * 0.70710678118654752f)));
        } else if (EPI == 3) {
          outf[row * N + col] += v + bias[col];
        } else if (EPI == 4) {
          // un-permute window-ordered row -> token row, fuse residual add
          int winr = (int)(row >> 6), pos = (int)(row & 63);
          int bI = winr >> 6, wy = (winr >> 3) & 7, wx = winr & 7;
          size_t tt = (size_t)bI * 4096 + (size_t)(wy * 8 + (pos >> 3)) * 64 + wx * 8 + (pos & 7);
          outf[tt * 256 + col] = v + bias[col] + xres[tt * 256 + col];
        }
      }
    }
  }
}

// ---------------------------------------------------------------- window attention
__global__ __launch_bounds__(256) void attn_win(
    const unsigned short* __restrict__ qkv, const float* __restrict__ table,
    unsigned short* __restrict__ out) {
  __shared__ float tbl[1800];
  __shared__ __align__(16) unsigned short p_lds[4][64 * 72];
  __shared__ __align__(16) unsigned short vt_lds[4][32 * 72];
  const int tid = threadIdx.x, lane = tid & 63, wid = tid >> 6;
  const int cl = lane & 15, cg = lane >> 4;
  for (int i = tid; i < 1800; i += 256) tbl[i] = table[i];
  __syncthreads();
  const size_t wbase = (size_t)blockIdx.x * 64;
  unsigned short* P = p_lds[wid];
  unsigned short* VT = vt_lds[wid];
  const float scale = 0.17677669529663687f;

  for (int hh = 0; hh < 2; ++hh) {
    const int h = wid + hh * 4;
    const int qoff = h * 32, koff = 256 + h * 32, voff = 512 + h * 32;
    bf16x8 qf[4], kf[4];
    #pragma unroll
    for (int mi = 0; mi < 4; ++mi)
      qf[mi] = *(const bf16x8*)&qkv[(wbase + mi * 16 + cl) * 768 + qoff + cg * 8];
    #pragma unroll
    for (int nj = 0; nj < 4; ++nj)
      kf[nj] = *(const bf16x8*)&qkv[(wbase + nj * 16 + cl) * 768 + koff + cg * 8];
    f32x4 S[4][4] = {};
    #pragma unroll
    for (int mi = 0; mi < 4; ++mi)
      #pragma unroll
      for (int nj = 0; nj < 4; ++nj)
        S[mi][nj] = __builtin_amdgcn_mfma_f32_16x16x32_bf16(qf[mi], kf[nj], S[mi][nj], 0, 0, 0);

    {
      const unsigned short* vrow = &qkv[(wbase + lane) * 768 + voff];
      unsigned short tmp[32];
      #pragma unroll
      for (int p = 0; p < 4; ++p) *(uint4*)&tmp[p * 8] = ((const uint4*)vrow)[p];
      #pragma unroll
      for (int d = 0; d < 32; ++d) VT[d * 72 + lane] = tmp[d];
    }

    float rs[4][4];
    #pragma unroll
    for (int mi = 0; mi < 4; ++mi) {
      #pragma unroll
      for (int r = 0; r < 4; ++r) {
        const int i = mi * 16 + cg * 4 + r;
        const int yi = i >> 3, xi = i & 7;
        float v[4];
        float m = -1e30f;
        #pragma unroll
        for (int nj = 0; nj < 4; ++nj) {
          const int j = nj * 16 + cl;
          const int yj = j >> 3, xj = j & 7;
          float bia = tbl[((yi - yj + 7) * 15 + (xi - xj + 7)) * 8 + h];
          v[nj] = S[mi][nj][r] * scale + bia;
          m = fmaxf(m, v[nj]);
        }
        #pragma unroll
        for (int mk = 1; mk < 16; mk <<= 1) m = fmaxf(m, __shfl_xor(m, mk));
        float s = 0.0f;
        #pragma unroll
        for (int nj = 0; nj < 4; ++nj) { v[nj] = expf(v[nj] - m); s += v[nj]; }
        #pragma unroll
        for (int mk = 1; mk < 16; mk <<= 1) s += __shfl_xor(s, mk);
        rs[mi][r] = s;
        #pragma unroll
        for (int nj = 0; nj < 4; ++nj) P[i * 72 + nj * 16 + cl] = f2bf(v[nj]);
      }
    }

    f32x4 O[4][2] = {};
    #pragma unroll
    for (int ks = 0; ks < 2; ++ks) {
      bf16x8 pa[4], vb[2];
      #pragma unroll
      for (int mi = 0; mi < 4; ++mi)
        pa[mi] = *(const bf16x8*)&P[(mi * 16 + cl) * 72 + ks * 32 + cg * 8];
      #pragma unroll
      for (int nd = 0; nd < 2; ++nd)
        vb[nd] = *(const bf16x8*)&VT[(nd * 16 + cl) * 72 + ks * 32 + cg * 8];
      #pragma unroll
      for (int mi = 0; mi < 4; ++mi)
        #pragma unroll
        for (int nd = 0; nd < 2; ++nd)
          O[mi][nd] = __builtin_amdgcn_mfma_f32_16x16x32_bf16(pa[mi], vb[nd], O[mi][nd], 0, 0, 0);
    }

    #pragma unroll
    for (int mi = 0; mi < 4; ++mi)
      #pragma unroll
      for (int nd = 0; nd < 2; ++nd)
        #pragma unroll
        for (int r = 0; r < 4; ++r) {
          float val = O[mi][nd][r] / rs[mi][r];
          out[(wbase + mi * 16 + cg * 4 + r) * 256 + h * 32 + nd * 16 + cl] = f2bf(val);
        }
  }
}

// ---------------------------------------------------------------- LN2 (reads x2 from d_out)
__global__ __launch_bounds__(256) void ln2_kernel(
    const float* __restrict__ x2, const float* __restrict__ g, const float* __restrict__ b,
    unsigned short* __restrict__ h2) {
  int lane = threadIdx.x & 63, wid = threadIdx.x >> 6;
  size_t t = (size_t)blockIdx.x * 4 + wid;
  float4 v = ((const float4*)(x2 + t * 256))[lane];
  float s = v.x + v.y + v.z + v.w;
  #pragma unroll
  for (int m = 1; m < 64; m <<= 1) s += __shfl_xor(s, m);
  float mean = s * (1.0f / 256.0f);
  float dx = v.x - mean, dy = v.y - mean, dz = v.z - mean, dw = v.w - mean;
  float q = dx * dx + dy * dy + dz * dz + dw * dw;
  #pragma unroll
  for (int m = 1; m < 64; m <<= 1) q += __shfl_xor(q, m);
  float rstd = rsqrtf(q * (1.0f / 256.0f) + 1e-5f);
  float4 gg = ((const float4*)g)[lane];
  float4 bb = ((const float4*)b)[lane];
  uint2 o;
  o.x = f2bf(dx * rstd * gg.x + bb.x) | ((unsigned int)f2bf(dy * rstd * gg.y + bb.y) << 16);
  o.y = f2bf(dz * rstd * gg.z + bb.z) | ((unsigned int)f2bf(dw * rstd * gg.w + bb.w) << 16);
  ((uint2*)(h2 + t * 256))[lane] = o;
}

// ---------------------------------------------------------------- launch
extern "C" void kernel_launch(void* const* d_in, const int* in_sizes, int n_in,
                              void* d_out, int out_size, void* d_ws, size_t ws_size,
                              hipStream_t stream) {
  (void)in_sizes; (void)n_in; (void)out_size; (void)ws_size;
  const float* x       = (const float*)d_in[0];
  const float* ln1_g   = (const float*)d_in[3];
  const float* ln1_b   = (const float*)d_in[4];
  const float* qkv_w   = (const float*)d_in[5];
  const float* proj_w  = (const float*)d_in[6];
  const float* proj_b  = (const float*)d_in[7];
  const float* rel_tbl = (const float*)d_in[8];
  const float* ln2_g   = (const float*)d_in[9];
  const float* ln2_b   = (const float*)d_in[10];
  const float* fc1_w   = (const float*)d_in[11];
  const float* fc1_b   = (const float*)d_in[12];
  const float* fc2_w   = (const float*)d_in[13];
  const float* fc2_b   = (const float*)d_in[14];
  float* out = (float*)d_out;

  char* ws = (char*)d_ws;
  const size_t OFF_XN   = 1572864;                 // weights: 786432*2 B
  const size_t OFF_QKV  = OFF_XN + 33554432;       // xn/h2: 65536*256*2
  const size_t OFF_ATTN = OFF_QKV + 100663296;     // qkv: 65536*768*2
  unsigned short* Wt      = (unsigned short*)ws;
  unsigned short* xn      = (unsigned short*)(ws + OFF_XN);
  unsigned short* h2      = xn;                          // reuse after QKV GEMM
  unsigned short* qkv     = (unsigned short*)(ws + OFF_QKV);
  unsigned short* fc1out  = (unsigned short*)(ws + OFF_QKV); // spans qkv+attn regions
  unsigned short* attnout = (unsigned short*)(ws + OFF_ATTN);

  prep_w<<<3072, 256, 0, stream>>>(qkv_w, proj_w, fc1_w, fc2_w, Wt);
  ln1_kernel<<<16384, 256, 0, stream>>>(x, ln1_g, ln1_b, xn);
  gemm_bt<0><<<dim3(6, 512), 256, 0, stream>>>(xn, Wt, qkv, nullptr, nullptr, nullptr, 65536, 768, 256);
  attn_win<<<1024, 256, 0, stream>>>(qkv, rel_tbl, attnout);
  // proj: writes x2 = x + attn_proj + bias directly to d_out (un-permuted)
  gemm_bt<4><<<dim3(2, 512), 256, 0, stream>>>(attnout, Wt + 196608, nullptr, out, proj_b, x, 65536, 256, 256);
  ln2_kernel<<<16384, 256, 0, stream>>>(out, ln2_g, ln2_b, h2);
  gemm_bt<1><<<dim3(8, 512), 256, 0, stream>>>(h2, Wt + 262144, fc1out, nullptr, fc1_b, nullptr, 65536, 1024, 256);
  gemm_bt<3><<<dim3(2, 512), 256, 0, stream>>>(fc1out, Wt + 524288, nullptr, out, fc2_b, nullptr, 65536, 256, 1024);
}

// Round 4
// 449.443 us; speedup vs baseline: 1.1550x; 1.0131x over previous
//
#include <hip/hip_runtime.h>
#include <hip/hip_bf16.h>

typedef __attribute__((ext_vector_type(8))) short bf16x8;
typedef __attribute__((ext_vector_type(4))) float f32x4;

typedef __attribute__((address_space(3))) void LdsVoid;
typedef const __attribute__((address_space(1))) void GblVoid;

__device__ __forceinline__ void gload16(const void* g, void* l) {
  __builtin_amdgcn_global_load_lds((GblVoid*)g, (LdsVoid*)l, 16, 0, 0);
}

__device__ __forceinline__ unsigned short f2bf(float f) {
  union { float f; unsigned int u; } x; x.f = f;
  unsigned int r = (x.u + 0x7fffu + ((x.u >> 16) & 1u)) >> 16;
  return (unsigned short)r;
}

// fast GELU: tanh form, overflow-safe, one v_exp_f32. |err| vs exact erf ~1e-3.
__device__ __forceinline__ float gelu_f(float t) {
  float u = t * (0.7978845608028654f + 0.03567740814f * t * t);
  float e = __expf(2.0f * u);
  float th = 1.0f - 2.0f / (e + 1.0f);
  return 0.5f * t * (1.0f + th);
}

// ---------------------------------------------------------------- weights prep
// Layout in ws (ushort elems): qkv_wt[768][256] @0, proj_wt[256][256] @196608,
// fc1_wt[1024][256] @262144, fc2_wt[256][1024] @524288. Total 786432 elems.
__global__ __launch_bounds__(256) void prep_w(
    const float* __restrict__ qw, const float* __restrict__ pw,
    const float* __restrict__ f1, const float* __restrict__ f2,
    unsigned short* __restrict__ out) {
  int idx = blockIdx.x * 256 + threadIdx.x;
  if (idx < 196608) { int n = idx >> 8, k = idx & 255; out[idx] = f2bf(qw[k * 768 + n]); return; }
  int i2 = idx - 196608;
  if (i2 < 65536) { int n = i2 >> 8, k = i2 & 255; out[idx] = f2bf(pw[k * 256 + n]); return; }
  int i3 = i2 - 65536;
  if (i3 < 262144) { int n = i3 >> 8, k = i3 & 255; out[idx] = f2bf(f1[k * 1024 + n]); return; }
  int i4 = i3 - 262144;
  { int n = i4 >> 10, k = i4 & 1023; out[idx] = f2bf(f2[k * 256 + n]); }
}

// ---------------------------------------------------------------- LN1 + window permute
__global__ __launch_bounds__(256) void ln1_kernel(
    const float* __restrict__ x, const float* __restrict__ g, const float* __restrict__ b,
    unsigned short* __restrict__ xn) {
  int lane = threadIdx.x & 63, wid = threadIdx.x >> 6;
  size_t t = (size_t)blockIdx.x * 4 + wid;
  float4 v = ((const float4*)(x + t * 256))[lane];
  float s = v.x + v.y + v.z + v.w;
  #pragma unroll
  for (int m = 1; m < 64; m <<= 1) s += __shfl_xor(s, m);
  float mean = s * (1.0f / 256.0f);
  float dx = v.x - mean, dy = v.y - mean, dz = v.z - mean, dw = v.w - mean;
  float q = dx * dx + dy * dy + dz * dz + dw * dw;
  #pragma unroll
  for (int m = 1; m < 64; m <<= 1) q += __shfl_xor(q, m);
  float rstd = rsqrtf(q * (1.0f / 256.0f) + 1e-5f);
  float4 gg = ((const float4*)g)[lane];
  float4 bb = ((const float4*)b)[lane];
  unsigned int o0 = f2bf(dx * rstd * gg.x + bb.x) | ((unsigned int)f2bf(dy * rstd * gg.y + bb.y) << 16);
  unsigned int o1 = f2bf(dz * rstd * gg.z + bb.z) | ((unsigned int)f2bf(dw * rstd * gg.w + bb.w) << 16);
  int bI = (int)(t >> 12), rem = (int)t & 4095, y = rem >> 6, xc = rem & 63;
  size_t r = ((size_t)(bI * 64 + (y >> 3) * 8 + (xc >> 3))) * 64 + (y & 7) * 8 + (xc & 7);
  uint2 o; o.x = o0; o.y = o1;
  ((uint2*)(xn + r * 256))[lane] = o;
}

// ---------------------------------------------------------------- GEMM (BK=64, 2-buf, counted vmcnt)
// C[M,N] = A[M,K](bf16,rm) x Bt[N,K](bf16,rm = B^T). 128x128 tile, BK=64,
// 4 waves 2x2, 2-buffer LDS (64KB), 2 tiles in flight, chunk-XOR swizzle,
// XCD chunk swizzle. MFMA operands SWAPPED -> lane holds row=cl, 4 consecutive
// cols (cg*4+reg) => vectorized epilogue stores.
// EPI: 0 = bf16 out; 1 = bf16(gelu(acc+bias)); 3 = f32 out += acc+bias;
//      4 = f32 out[unpermute(row)] = acc + bias + xres[unpermute(row)]
template <int EPI>
__global__ __launch_bounds__(256) void gemm_bt(
    const unsigned short* __restrict__ A, const unsigned short* __restrict__ Bt,
    unsigned short* __restrict__ outb, float* __restrict__ outf,
    const float* __restrict__ bias, const float* __restrict__ xres,
    int M, int N, int K) {
  __shared__ __align__(16) unsigned short lds[2 * 16384];  // 64KB
  const int tid = threadIdx.x;
  const int lane = tid & 63, wid = tid >> 6;
  const int cl = lane & 15, cg = lane >> 4;
  const unsigned nwg = gridDim.x * gridDim.y;
  const unsigned orig = blockIdx.y * gridDim.x + blockIdx.x;
  const unsigned virt = (orig & 7) * (nwg >> 3) + (orig >> 3);
  const unsigned bx = virt % gridDim.x, by = virt / gridDim.x;
  const size_t m0 = (size_t)by * 128;
  const size_t n0 = (size_t)bx * 128;
  const int wr = wid >> 1, wc = wid & 1;
  f32x4 acc[4][4] = {};

  const int r8 = lane >> 3;
  const int gsw = ((lane & 7) ^ r8) * 8;  // elems
  const unsigned short* aStage = A + (m0 + wid * 32 + r8) * K + gsw;
  const unsigned short* bStage = Bt + (n0 + wid * 32 + r8) * K + gsw;
  const size_t jstep = (size_t)8 * K;
  const int nt = K >> 6;

  #define STAGE(T, B)                                                   \
    { const int ko_ = (T) * 64;                                         \
      unsigned short* la_ = lds + (B) * 16384 + wid * 2048;             \
      unsigned short* lb_ = la_ + 8192;                                 \
      _Pragma("unroll")                                                 \
      for (int j = 0; j < 4; ++j) {                                     \
        gload16(aStage + ko_ + j * jstep, la_ + j * 512);               \
        gload16(bStage + ko_ + j * jstep, lb_ + j * 512);               \
      } }

  bf16x8 af[2][4], bfr[2][4];
  #define READF(B)                                                          \
    { const unsigned short* base_ = lds + (B) * 16384;                      \
      _Pragma("unroll")                                                     \
      for (int kk = 0; kk < 2; ++kk)                                        \
        _Pragma("unroll")                                                   \
        for (int i = 0; i < 4; ++i) {                                       \
          const int sl_ = ((kk * 4 + cg) ^ (cl & 7)) * 8;                   \
          af[kk][i]  = *(const bf16x8*)(base_ + (wr * 64 + i * 16 + cl) * 64 + sl_);        \
          bfr[kk][i] = *(const bf16x8*)(base_ + 8192 + (wc * 64 + i * 16 + cl) * 64 + sl_); \
        } }

  // swapped operands: m-dim = Bt rows (C cols), n-dim = A rows (C rows)
  #define MFMAS()                                                           \
    { _Pragma("unroll")                                                     \
      for (int kk = 0; kk < 2; ++kk)                                        \
        _Pragma("unroll")                                                   \
        for (int mi = 0; mi < 4; ++mi)                                      \
          _Pragma("unroll")                                                 \
          for (int ni = 0; ni < 4; ++ni)                                    \
            acc[mi][ni] = __builtin_amdgcn_mfma_f32_16x16x32_bf16(bfr[kk][ni], af[kk][mi], acc[mi][ni], 0, 0, 0); }

  STAGE(0, 0);
  STAGE(1, 1);
  for (int t = 0; t < nt; ++t) {
    if (t == nt - 1) { asm volatile("s_waitcnt vmcnt(0)" ::: "memory"); }
    else             { asm volatile("s_waitcnt vmcnt(8)" ::: "memory"); }
    __builtin_amdgcn_s_barrier();           // tile t visible to all waves
    READF(t & 1);
    __builtin_amdgcn_sched_barrier(0);
    asm volatile("s_waitcnt lgkmcnt(0)" ::: "memory");  // my reads of buf done
    __builtin_amdgcn_s_barrier();           // all waves done reading buf
    __builtin_amdgcn_sched_barrier(0);
    if (t + 2 < nt) STAGE(t + 2, t & 1);    // overwrite freed buffer
    MFMAS();
  }
  #undef STAGE
  #undef READF
  #undef MFMAS

  // lane cl = row (within 16-tile), cg*4..+3 = 4 consecutive cols
  #pragma unroll
  for (int mi = 0; mi < 4; ++mi) {
    const size_t row = m0 + wr * 64 + mi * 16 + cl;
    #pragma unroll
    for (int ni = 0; ni < 4; ++ni) {
      const size_t col = n0 + wc * 64 + ni * 16 + cg * 4;
      f32x4 v = acc[mi][ni];
      if (EPI == 0) {
        uint2 o;
        o.x = f2bf(v[0]) | ((unsigned int)f2bf(v[1]) << 16);
        o.y = f2bf(v[2]) | ((unsigned int)f2bf(v[3]) << 16);
        *(uint2*)&outb[row * N + col] = o;
      } else if (EPI == 1) {
        float4 bb = *(const float4*)&bias[col];
        float g0 = gelu_f(v[0] + bb.x), g1 = gelu_f(v[1] + bb.y);
        float g2 = gelu_f(v[2] + bb.z), g3 = gelu_f(v[3] + bb.w);
        uint2 o;
        o.x = f2bf(g0) | ((unsigned int)f2bf(g1) << 16);
        o.y = f2bf(g2) | ((unsigned int)f2bf(g3) << 16);
        *(uint2*)&outb[row * N + col] = o;
      } else if (EPI == 3) {
        float4 bb = *(const float4*)&bias[col];
        float4* p = (float4*)&outf[row * N + col];
        float4 old = *p;
        old.x += v[0] + bb.x; old.y += v[1] + bb.y;
        old.z += v[2] + bb.z; old.w += v[3] + bb.w;
        *p = old;
      } else if (EPI == 4) {
        int winr = (int)(row >> 6), pos = (int)(row & 63);
        int bI = winr >> 6, wy = (winr >> 3) & 7, wx = winr & 7;
        size_t tt = (size_t)bI * 4096 + (size_t)(wy * 8 + (pos >> 3)) * 64 + wx * 8 + (pos & 7);
        float4 bb = *(const float4*)&bias[col];
        float4 xr = *(const float4*)&xres[tt * 256 + col];
        float4 o;
        o.x = v[0] + bb.x + xr.x; o.y = v[1] + bb.y + xr.y;
        o.z = v[2] + bb.z + xr.z; o.w = v[3] + bb.w + xr.w;
        *(float4*)&outf[tt * 256 + col] = o;
      }
    }
  }
}

// ---------------------------------------------------------------- window attention
// P normalized by 1/rowsum before bf16 quantization; PV mfma swapped so the
// out store is uint2 (4 consecutive dims per lane).
__global__ __launch_bounds__(256) void attn_win(
    const unsigned short* __restrict__ qkv, const float* __restrict__ table,
    unsigned short* __restrict__ out) {
  __shared__ float tbl[1800];
  __shared__ __align__(16) unsigned short p_lds[4][64 * 72];
  __shared__ __align__(16) unsigned short vt_lds[4][32 * 72];
  const int tid = threadIdx.x, lane = tid & 63, wid = tid >> 6;
  const int cl = lane & 15, cg = lane >> 4;
  for (int i = tid; i < 1800; i += 256) tbl[i] = table[i];
  __syncthreads();
  const size_t wbase = (size_t)blockIdx.x * 64;
  unsigned short* P = p_lds[wid];
  unsigned short* VT = vt_lds[wid];
  const float scale = 0.17677669529663687f;

  for (int hh = 0; hh < 2; ++hh) {
    const int h = wid + hh * 4;
    const int qoff = h * 32, koff = 256 + h * 32, voff = 512 + h * 32;
    bf16x8 qf[4], kf[4];
    #pragma unroll
    for (int mi = 0; mi < 4; ++mi)
      qf[mi] = *(const bf16x8*)&qkv[(wbase + mi * 16 + cl) * 768 + qoff + cg * 8];
    #pragma unroll
    for (int nj = 0; nj < 4; ++nj)
      kf[nj] = *(const bf16x8*)&qkv[(wbase + nj * 16 + cl) * 768 + koff + cg * 8];
    f32x4 S[4][4] = {};
    #pragma unroll
    for (int mi = 0; mi < 4; ++mi)
      #pragma unroll
      for (int nj = 0; nj < 4; ++nj)
        S[mi][nj] = __builtin_amdgcn_mfma_f32_16x16x32_bf16(qf[mi], kf[nj], S[mi][nj], 0, 0, 0);

    {
      const unsigned short* vrow = &qkv[(wbase + lane) * 768 + voff];
      unsigned short tmp[32];
      #pragma unroll
      for (int p = 0; p < 4; ++p) *(uint4*)&tmp[p * 8] = ((const uint4*)vrow)[p];
      #pragma unroll
      for (int d = 0; d < 32; ++d) VT[d * 72 + lane] = tmp[d];
    }

    #pragma unroll
    for (int mi = 0; mi < 4; ++mi) {
      #pragma unroll
      for (int r = 0; r < 4; ++r) {
        const int i = mi * 16 + cg * 4 + r;
        const int yi = i >> 3, xi = i & 7;
        float v[4];
        float m = -1e30f;
        #pragma unroll
        for (int nj = 0; nj < 4; ++nj) {
          const int j = nj * 16 + cl;
          const int yj = j >> 3, xj = j & 7;
          float bia = tbl[((yi - yj + 7) * 15 + (xi - xj + 7)) * 8 + h];
          v[nj] = S[mi][nj][r] * scale + bia;
          m = fmaxf(m, v[nj]);
        }
        #pragma unroll
        for (int mk = 1; mk < 16; mk <<= 1) m = fmaxf(m, __shfl_xor(m, mk));
        float s = 0.0f;
        #pragma unroll
        for (int nj = 0; nj < 4; ++nj) { v[nj] = expf(v[nj] - m); s += v[nj]; }
        #pragma unroll
        for (int mk = 1; mk < 16; mk <<= 1) s += __shfl_xor(s, mk);
        const float rinv = 1.0f / s;
        #pragma unroll
        for (int nj = 0; nj < 4; ++nj) P[i * 72 + nj * 16 + cl] = f2bf(v[nj] * rinv);
      }
    }

    f32x4 O[4][2] = {};
    #pragma unroll
    for (int ks = 0; ks < 2; ++ks) {
      bf16x8 pa[4], vb[2];
      #pragma unroll
      for (int mi = 0; mi < 4; ++mi)
        pa[mi] = *(const bf16x8*)&P[(mi * 16 + cl) * 72 + ks * 32 + cg * 8];
      #pragma unroll
      for (int nd = 0; nd < 2; ++nd)
        vb[nd] = *(const bf16x8*)&VT[(nd * 16 + cl) * 72 + ks * 32 + cg * 8];
      #pragma unroll
      for (int mi = 0; mi < 4; ++mi)
        #pragma unroll
        for (int nd = 0; nd < 2; ++nd)
          O[mi][nd] = __builtin_amdgcn_mfma_f32_16x16x32_bf16(vb[nd], pa[mi], O[mi][nd], 0, 0, 0);
    }

    // lane cl = token (within mi-tile), cg*4..+3 = 4 consecutive dims in nd-tile
    #pragma unroll
    for (int mi = 0; mi < 4; ++mi)
      #pragma unroll
      for (int nd = 0; nd < 2; ++nd) {
        uint2 o;
        o.x = f2bf(O[mi][nd][0]) | ((unsigned int)f2bf(O[mi][nd][1]) << 16);
        o.y = f2bf(O[mi][nd][2]) | ((unsigned int)f2bf(O[mi][nd][3]) << 16);
        *(uint2*)&out[(wbase + mi * 16 + cl) * 256 + h * 32 + nd * 16 + cg * 4] = o;
      }
  }
}

// ---------------------------------------------------------------- LN2 (reads x2 from d_out)
__global__ __launch_bounds__(256) void ln2_kernel(
    const float* __restrict__ x2, const float* __restrict__ g, const float* __restrict__ b,
    unsigned short* __restrict__ h2) {
  int lane = threadIdx.x & 63, wid = threadIdx.x >> 6;
  size_t t = (size_t)blockIdx.x * 4 + wid;
  float4 v = ((const float4*)(x2 + t * 256))[lane];
  float s = v.x + v.y + v.z + v.w;
  #pragma unroll
  for (int m = 1; m < 64; m <<= 1) s += __shfl_xor(s, m);
  float mean = s * (1.0f / 256.0f);
  float dx = v.x - mean, dy = v.y - mean, dz = v.z - mean, dw = v.w - mean;
  float q = dx * dx + dy * dy + dz * dz + dw * dw;
  #pragma unroll
  for (int m = 1; m < 64; m <<= 1) q += __shfl_xor(q, m);
  float rstd = rsqrtf(q * (1.0f / 256.0f) + 1e-5f);
  float4 gg = ((const float4*)g)[lane];
  float4 bb = ((const float4*)b)[lane];
  uint2 o;
  o.x = f2bf(dx * rstd * gg.x + bb.x) | ((unsigned int)f2bf(dy * rstd * gg.y + bb.y) << 16);
  o.y = f2bf(dz * rstd * gg.z + bb.z) | ((unsigned int)f2bf(dw * rstd * gg.w + bb.w) << 16);
  ((uint2*)(h2 + t * 256))[lane] = o;
}

// ---------------------------------------------------------------- launch
extern "C" void kernel_launch(void* const* d_in, const int* in_sizes, int n_in,
                              void* d_out, int out_size, void* d_ws, size_t ws_size,
                              hipStream_t stream) {
  (void)in_sizes; (void)n_in; (void)out_size; (void)ws_size;
  const float* x       = (const float*)d_in[0];
  const float* ln1_g   = (const float*)d_in[3];
  const float* ln1_b   = (const float*)d_in[4];
  const float* qkv_w   = (const float*)d_in[5];
  const float* proj_w  = (const float*)d_in[6];
  const float* proj_b  = (const float*)d_in[7];
  const float* rel_tbl = (const float*)d_in[8];
  const float* ln2_g   = (const float*)d_in[9];
  const float* ln2_b   = (const float*)d_in[10];
  const float* fc1_w   = (const float*)d_in[11];
  const float* fc1_b   = (const float*)d_in[12];
  const float* fc2_w   = (const float*)d_in[13];
  const float* fc2_b   = (const float*)d_in[14];
  float* out = (float*)d_out;

  char* ws = (char*)d_ws;
  const size_t OFF_XN   = 1572864;                 // weights: 786432*2 B
  const size_t OFF_QKV  = OFF_XN + 33554432;       // xn/h2: 65536*256*2
  const size_t OFF_ATTN = OFF_QKV + 100663296;     // qkv: 65536*768*2
  unsigned short* Wt      = (unsigned short*)ws;
  unsigned short* xn      = (unsigned short*)(ws + OFF_XN);
  unsigned short* h2      = xn;                          // reuse after QKV GEMM
  unsigned short* qkv     = (unsigned short*)(ws + OFF_QKV);
  unsigned short* fc1out  = (unsigned short*)(ws + OFF_QKV); // spans qkv+attn regions
  unsigned short* attnout = (unsigned short*)(ws + OFF_ATTN);

  prep_w<<<3072, 256, 0, stream>>>(qkv_w, proj_w, fc1_w, fc2_w, Wt);
  ln1_kernel<<<16384, 256, 0, stream>>>(x, ln1_g, ln1_b, xn);
  gemm_bt<0><<<dim3(6, 512), 256, 0, stream>>>(xn, Wt, qkv, nullptr, nullptr, nullptr, 65536, 768, 256);
  attn_win<<<1024, 256, 0, stream>>>(qkv, rel_tbl, attnout);
  // proj: writes x2 = x + attn_proj + bias directly to d_out (un-permuted)
  gemm_bt<4><<<dim3(2, 512), 256, 0, stream>>>(attnout, Wt + 196608, nullptr, out, proj_b, x, 65536, 256, 256);
  ln2_kernel<<<16384, 256, 0, stream>>>(out, ln2_g, ln2_b, h2);
  gemm_bt<1><<<dim3(8, 512), 256, 0, stream>>>(h2, Wt + 262144, fc1out, nullptr, fc1_b, nullptr, 65536, 1024, 256);
  gemm_bt<3><<<dim3(2, 512), 256, 0, stream>>>(fc1out, Wt + 524288, nullptr, out, fc2_b, nullptr, 65536, 256, 1024);
}

// Round 5
// 430.559 us; speedup vs baseline: 1.2057x; 1.0439x over previous
//
#include <hip/hip_runtime.h>
#include <hip/hip_bf16.h>

typedef __attribute__((ext_vector_type(8))) short bf16x8;
typedef __attribute__((ext_vector_type(4))) float f32x4;

typedef __attribute__((address_space(3))) void LdsVoid;
typedef const __attribute__((address_space(1))) void GblVoid;

__device__ __forceinline__ void gload16(const void* g, void* l) {
  __builtin_amdgcn_global_load_lds((GblVoid*)g, (LdsVoid*)l, 16, 0, 0);
}

__device__ __forceinline__ unsigned short f2bf(float f) {
  union { float f; unsigned int u; } x; x.f = f;
  unsigned int r = (x.u + 0x7fffu + ((x.u >> 16) & 1u)) >> 16;
  return (unsigned short)r;
}

// fast GELU: tanh form, no division (rcp intrinsic), one v_exp_f32.
__device__ __forceinline__ float gelu_f(float t) {
  float u = t * (0.7978845608028654f + 0.03567740814f * t * t);
  float e = __expf(2.0f * u);
  float th = 1.0f - 2.0f * __builtin_amdgcn_rcpf(e + 1.0f);
  return 0.5f * t * (1.0f + th);
}

// ---------------------------------------------------------------- weights prep
// Layout in ws (ushort elems): qkv_wt[768][256] @0, proj_wt[256][256] @196608,
// fc1_wt[1024][256] @262144, fc2_wt[256][1024] @524288. Total 786432 elems.
__global__ __launch_bounds__(256) void prep_w(
    const float* __restrict__ qw, const float* __restrict__ pw,
    const float* __restrict__ f1, const float* __restrict__ f2,
    unsigned short* __restrict__ out) {
  int idx = blockIdx.x * 256 + threadIdx.x;
  if (idx < 196608) { int n = idx >> 8, k = idx & 255; out[idx] = f2bf(qw[k * 768 + n]); return; }
  int i2 = idx - 196608;
  if (i2 < 65536) { int n = i2 >> 8, k = i2 & 255; out[idx] = f2bf(pw[k * 256 + n]); return; }
  int i3 = i2 - 65536;
  if (i3 < 262144) { int n = i3 >> 8, k = i3 & 255; out[idx] = f2bf(f1[k * 1024 + n]); return; }
  int i4 = i3 - 262144;
  { int n = i4 >> 10, k = i4 & 1023; out[idx] = f2bf(f2[k * 256 + n]); }
}

// ---------------------------------------------------------------- LN1 + window permute
__global__ __launch_bounds__(256) void ln1_kernel(
    const float* __restrict__ x, const float* __restrict__ g, const float* __restrict__ b,
    unsigned short* __restrict__ xn) {
  int lane = threadIdx.x & 63, wid = threadIdx.x >> 6;
  size_t t = (size_t)blockIdx.x * 4 + wid;
  float4 v = ((const float4*)(x + t * 256))[lane];
  float s = v.x + v.y + v.z + v.w;
  #pragma unroll
  for (int m = 1; m < 64; m <<= 1) s += __shfl_xor(s, m);
  float mean = s * (1.0f / 256.0f);
  float dx = v.x - mean, dy = v.y - mean, dz = v.z - mean, dw = v.w - mean;
  float q = dx * dx + dy * dy + dz * dz + dw * dw;
  #pragma unroll
  for (int m = 1; m < 64; m <<= 1) q += __shfl_xor(q, m);
  float rstd = rsqrtf(q * (1.0f / 256.0f) + 1e-5f);
  float4 gg = ((const float4*)g)[lane];
  float4 bb = ((const float4*)b)[lane];
  unsigned int o0 = f2bf(dx * rstd * gg.x + bb.x) | ((unsigned int)f2bf(dy * rstd * gg.y + bb.y) << 16);
  unsigned int o1 = f2bf(dz * rstd * gg.z + bb.z) | ((unsigned int)f2bf(dw * rstd * gg.w + bb.w) << 16);
  int bI = (int)(t >> 12), rem = (int)t & 4095, y = rem >> 6, xc = rem & 63;
  size_t r = ((size_t)(bI * 64 + (y >> 3) * 8 + (xc >> 3))) * 64 + (y & 7) * 8 + (xc & 7);
  uint2 o; o.x = o0; o.y = o1;
  ((uint2*)(xn + r * 256))[lane] = o;
}

// ---------------------------------------------------------------- GEMM (BK=32, 2-buf 32KB, counted vmcnt)
// C[M,N] = A[M,K](bf16,rm) x Bt[N,K](bf16,rm = B^T). 128x128 tile, BK=32,
// 4 waves 2x2, 2-buffer LDS (32KB -> 4-5 blocks/CU), counted vmcnt(4),
// chunk-XOR swizzle g(row)=(row>>1)&3 over 4 slots (2-way = free),
// XCD chunk swizzle. MFMA operands swapped -> lane holds row=cl, 4 consecutive
// cols => vectorized epilogue.
// EPI: 0 = bf16 out; 1 = bf16(gelu(acc+bias)); 3 = f32 out += acc+bias;
//      4 = f32 out[unpermute(row)] = acc + bias + xres[unpermute(row)]
template <int EPI>
__global__ __launch_bounds__(256) void gemm_bt(
    const unsigned short* __restrict__ A, const unsigned short* __restrict__ Bt,
    unsigned short* __restrict__ outb, float* __restrict__ outf,
    const float* __restrict__ bias, const float* __restrict__ xres,
    int M, int N, int K) {
  __shared__ __align__(16) unsigned short lds[2 * 8192];  // 32KB
  const int tid = threadIdx.x;
  const int lane = tid & 63, wid = tid >> 6;
  const int cl = lane & 15, cg = lane >> 4;
  const unsigned nwg = gridDim.x * gridDim.y;
  const unsigned orig = blockIdx.y * gridDim.x + blockIdx.x;
  const unsigned virt = (orig & 7) * (nwg >> 3) + (orig >> 3);
  const unsigned bx = virt % gridDim.x, by = virt / gridDim.x;
  const size_t m0 = (size_t)by * 128;
  const size_t n0 = (size_t)bx * 128;
  const int wr = wid >> 1, wc = wid & 1;
  f32x4 acc[4][4] = {};

  // staging: wave covers rows wid*32..+32 of A and B tiles; lane l -> row
  // r4=l>>2 (per 16-row gload), slot l&3. Slot s of row r holds logical chunk
  // s ^ g(r), g(r) = (r>>1)&3  => quarter-wave ds_read_b128 is 2-way (free).
  const int r4 = lane >> 2;
  const int gsw = ((lane & 3) ^ ((r4 >> 1) & 3)) * 8;  // elems
  const unsigned short* aStage = A + (m0 + wid * 32 + r4) * K + gsw;
  const unsigned short* bStage = Bt + (n0 + wid * 32 + r4) * K + gsw;
  const size_t jstep = (size_t)16 * K;
  const int nt = K >> 5;

  #define STAGE(T, B)                                                   \
    { const int ko_ = (T) * 32;                                         \
      unsigned short* la_ = lds + (B) * 8192 + wid * 1024;              \
      unsigned short* lb_ = la_ + 4096;                                 \
      gload16(aStage + ko_, la_);                                       \
      gload16(aStage + ko_ + jstep, la_ + 512);                         \
      gload16(bStage + ko_, lb_);                                       \
      gload16(bStage + ko_ + jstep, lb_ + 512); }

  bf16x8 af[4], bfr[4];
  const int sl_ = (cg ^ ((cl >> 1) & 3)) * 8;
  #define READF(B)                                                          \
    { const unsigned short* base_ = lds + (B) * 8192;                       \
      _Pragma("unroll")                                                     \
      for (int i = 0; i < 4; ++i) {                                         \
        af[i]  = *(const bf16x8*)(base_ + (wr * 64 + i * 16 + cl) * 32 + sl_);        \
        bfr[i] = *(const bf16x8*)(base_ + 4096 + (wc * 64 + i * 16 + cl) * 32 + sl_); \
      } }

  // swapped operands: output rows = A rows (af), cols = Bt rows (bfr)
  #define MFMAS()                                                           \
    { _Pragma("unroll")                                                     \
      for (int mi = 0; mi < 4; ++mi)                                        \
        _Pragma("unroll")                                                   \
        for (int ni = 0; ni < 4; ++ni)                                      \
          acc[mi][ni] = __builtin_amdgcn_mfma_f32_16x16x32_bf16(bfr[ni], af[mi], acc[mi][ni], 0, 0, 0); }

  STAGE(0, 0);
  STAGE(1, 1);
  for (int t = 0; t < nt; ++t) {
    if (t == nt - 1) { asm volatile("s_waitcnt vmcnt(0)" ::: "memory"); }
    else             { asm volatile("s_waitcnt vmcnt(4)" ::: "memory"); }
    __builtin_amdgcn_s_barrier();           // tile t visible to all waves
    READF(t & 1);
    __builtin_amdgcn_sched_barrier(0);
    asm volatile("s_waitcnt lgkmcnt(0)" ::: "memory");  // my reads of buf done
    __builtin_amdgcn_s_barrier();           // all waves done reading buf
    __builtin_amdgcn_sched_barrier(0);
    if (t + 2 < nt) STAGE(t + 2, t & 1);    // overwrite freed buffer
    MFMAS();
  }
  #undef STAGE
  #undef READF
  #undef MFMAS

  // lane cl = row (within 16-tile), cg*4..+3 = 4 consecutive cols
  #pragma unroll
  for (int mi = 0; mi < 4; ++mi) {
    const size_t row = m0 + wr * 64 + mi * 16 + cl;
    #pragma unroll
    for (int ni = 0; ni < 4; ++ni) {
      const size_t col = n0 + wc * 64 + ni * 16 + cg * 4;
      f32x4 v = acc[mi][ni];
      if (EPI == 0) {
        uint2 o;
        o.x = f2bf(v[0]) | ((unsigned int)f2bf(v[1]) << 16);
        o.y = f2bf(v[2]) | ((unsigned int)f2bf(v[3]) << 16);
        *(uint2*)&outb[row * N + col] = o;
      } else if (EPI == 1) {
        float4 bb = *(const float4*)&bias[col];
        float g0 = gelu_f(v[0] + bb.x), g1 = gelu_f(v[1] + bb.y);
        float g2 = gelu_f(v[2] + bb.z), g3 = gelu_f(v[3] + bb.w);
        uint2 o;
        o.x = f2bf(g0) | ((unsigned int)f2bf(g1) << 16);
        o.y = f2bf(g2) | ((unsigned int)f2bf(g3) << 16);
        *(uint2*)&outb[row * N + col] = o;
      } else if (EPI == 3) {
        float4 bb = *(const float4*)&bias[col];
        float4* p = (float4*)&outf[row * N + col];
        float4 old = *p;
        old.x += v[0] + bb.x; old.y += v[1] + bb.y;
        old.z += v[2] + bb.z; old.w += v[3] + bb.w;
        *p = old;
      } else if (EPI == 4) {
        int winr = (int)(row >> 6), pos = (int)(row & 63);
        int bI = winr >> 6, wy = (winr >> 3) & 7, wx = winr & 7;
        size_t tt = (size_t)bI * 4096 + (size_t)(wy * 8 + (pos >> 3)) * 64 + wx * 8 + (pos & 7);
        float4 bb = *(const float4*)&bias[col];
        float4 xr = *(const float4*)&xres[tt * 256 + col];
        float4 o;
        o.x = v[0] + bb.x + xr.x; o.y = v[1] + bb.y + xr.y;
        o.z = v[2] + bb.z + xr.z; o.w = v[3] + bb.w + xr.w;
        *(float4*)&outf[tt * 256 + col] = o;
      }
    }
  }
}

// ---------------------------------------------------------------- window attention
__global__ __launch_bounds__(256) void attn_win(
    const unsigned short* __restrict__ qkv, const float* __restrict__ table,
    unsigned short* __restrict__ out) {
  __shared__ float tbl[1800];
  __shared__ __align__(16) unsigned short p_lds[4][64 * 72];
  __shared__ __align__(16) unsigned short vt_lds[4][32 * 72];
  const int tid = threadIdx.x, lane = tid & 63, wid = tid >> 6;
  const int cl = lane & 15, cg = lane >> 4;
  for (int i = tid; i < 1800; i += 256) tbl[i] = table[i];
  __syncthreads();
  const size_t wbase = (size_t)blockIdx.x * 64;
  unsigned short* P = p_lds[wid];
  unsigned short* VT = vt_lds[wid];
  const float scale = 0.17677669529663687f;

  for (int hh = 0; hh < 2; ++hh) {
    const int h = wid + hh * 4;
    const int qoff = h * 32, koff = 256 + h * 32, voff = 512 + h * 32;
    bf16x8 qf[4], kf[4];
    #pragma unroll
    for (int mi = 0; mi < 4; ++mi)
      qf[mi] = *(const bf16x8*)&qkv[(wbase + mi * 16 + cl) * 768 + qoff + cg * 8];
    #pragma unroll
    for (int nj = 0; nj < 4; ++nj)
      kf[nj] = *(const bf16x8*)&qkv[(wbase + nj * 16 + cl) * 768 + koff + cg * 8];
    f32x4 S[4][4] = {};
    #pragma unroll
    for (int mi = 0; mi < 4; ++mi)
      #pragma unroll
      for (int nj = 0; nj < 4; ++nj)
        S[mi][nj] = __builtin_amdgcn_mfma_f32_16x16x32_bf16(qf[mi], kf[nj], S[mi][nj], 0, 0, 0);

    {
      const unsigned short* vrow = &qkv[(wbase + lane) * 768 + voff];
      unsigned short tmp[32];
      #pragma unroll
      for (int p = 0; p < 4; ++p) *(uint4*)&tmp[p * 8] = ((const uint4*)vrow)[p];
      #pragma unroll
      for (int d = 0; d < 32; ++d) VT[d * 72 + lane] = tmp[d];
    }

    #pragma unroll
    for (int mi = 0; mi < 4; ++mi) {
      #pragma unroll
      for (int r = 0; r < 4; ++r) {
        const int i = mi * 16 + cg * 4 + r;
        const int yi = i >> 3, xi = i & 7;
        float v[4];
        float m = -1e30f;
        #pragma unroll
        for (int nj = 0; nj < 4; ++nj) {
          const int j = nj * 16 + cl;
          const int yj = j >> 3, xj = j & 7;
          float bia = tbl[((yi - yj + 7) * 15 + (xi - xj + 7)) * 8 + h];
          v[nj] = S[mi][nj][r] * scale + bia;
          m = fmaxf(m, v[nj]);
        }
        #pragma unroll
        for (int mk = 1; mk < 16; mk <<= 1) m = fmaxf(m, __shfl_xor(m, mk));
        float s = 0.0f;
        #pragma unroll
        for (int nj = 0; nj < 4; ++nj) { v[nj] = __expf(v[nj] - m); s += v[nj]; }
        #pragma unroll
        for (int mk = 1; mk < 16; mk <<= 1) s += __shfl_xor(s, mk);
        const float rinv = __builtin_amdgcn_rcpf(s);
        #pragma unroll
        for (int nj = 0; nj < 4; ++nj) P[i * 72 + nj * 16 + cl] = f2bf(v[nj] * rinv);
      }
    }

    f32x4 O[4][2] = {};
    #pragma unroll
    for (int ks = 0; ks < 2; ++ks) {
      bf16x8 pa[4], vb[2];
      #pragma unroll
      for (int mi = 0; mi < 4; ++mi)
        pa[mi] = *(const bf16x8*)&P[(mi * 16 + cl) * 72 + ks * 32 + cg * 8];
      #pragma unroll
      for (int nd = 0; nd < 2; ++nd)
        vb[nd] = *(const bf16x8*)&VT[(nd * 16 + cl) * 72 + ks * 32 + cg * 8];
      #pragma unroll
      for (int mi = 0; mi < 4; ++mi)
        #pragma unroll
        for (int nd = 0; nd < 2; ++nd)
          O[mi][nd] = __builtin_amdgcn_mfma_f32_16x16x32_bf16(vb[nd], pa[mi], O[mi][nd], 0, 0, 0);
    }

    #pragma unroll
    for (int mi = 0; mi < 4; ++mi)
      #pragma unroll
      for (int nd = 0; nd < 2; ++nd) {
        uint2 o;
        o.x = f2bf(O[mi][nd][0]) | ((unsigned int)f2bf(O[mi][nd][1]) << 16);
        o.y = f2bf(O[mi][nd][2]) | ((unsigned int)f2bf(O[mi][nd][3]) << 16);
        *(uint2*)&out[(wbase + mi * 16 + cl) * 256 + h * 32 + nd * 16 + cg * 4] = o;
      }
  }
}

// ---------------------------------------------------------------- LN2 (reads x2 from d_out)
__global__ __launch_bounds__(256) void ln2_kernel(
    const float* __restrict__ x2, const float* __restrict__ g, const float* __restrict__ b,
    unsigned short* __restrict__ h2) {
  int lane = threadIdx.x & 63, wid = threadIdx.x >> 6;
  size_t t = (size_t)blockIdx.x * 4 + wid;
  float4 v = ((const float4*)(x2 + t * 256))[lane];
  float s = v.x + v.y + v.z + v.w;
  #pragma unroll
  for (int m = 1; m < 64; m <<= 1) s += __shfl_xor(s, m);
  float mean = s * (1.0f / 256.0f);
  float dx = v.x - mean, dy = v.y - mean, dz = v.z - mean, dw = v.w - mean;
  float q = dx * dx + dy * dy + dz * dz + dw * dw;
  #pragma unroll
  for (int m = 1; m < 64; m <<= 1) q += __shfl_xor(q, m);
  float rstd = rsqrtf(q * (1.0f / 256.0f) + 1e-5f);
  float4 gg = ((const float4*)g)[lane];
  float4 bb = ((const float4*)b)[lane];
  uint2 o;
  o.x = f2bf(dx * rstd * gg.x + bb.x) | ((unsigned int)f2bf(dy * rstd * gg.y + bb.y) << 16);
  o.y = f2bf(dz * rstd * gg.z + bb.z) | ((unsigned int)f2bf(dw * rstd * gg.w + bb.w) << 16);
  ((uint2*)(h2 + t * 256))[lane] = o;
}

// ---------------------------------------------------------------- launch
extern "C" void kernel_launch(void* const* d_in, const int* in_sizes, int n_in,
                              void* d_out, int out_size, void* d_ws, size_t ws_size,
                              hipStream_t stream) {
  (void)in_sizes; (void)n_in; (void)out_size; (void)ws_size;
  const float* x       = (const float*)d_in[0];
  const float* ln1_g   = (const float*)d_in[3];
  const float* ln1_b   = (const float*)d_in[4];
  const float* qkv_w   = (const float*)d_in[5];
  const float* proj_w  = (const float*)d_in[6];
  const float* proj_b  = (const float*)d_in[7];
  const float* rel_tbl = (const float*)d_in[8];
  const float* ln2_g   = (const float*)d_in[9];
  const float* ln2_b   = (const float*)d_in[10];
  const float* fc1_w   = (const float*)d_in[11];
  const float* fc1_b   = (const float*)d_in[12];
  const float* fc2_w   = (const float*)d_in[13];
  const float* fc2_b   = (const float*)d_in[14];
  float* out = (float*)d_out;

  char* ws = (char*)d_ws;
  const size_t OFF_XN   = 1572864;                 // weights: 786432*2 B
  const size_t OFF_QKV  = OFF_XN + 33554432;       // xn/h2: 65536*256*2
  const size_t OFF_ATTN = OFF_QKV + 100663296;     // qkv: 65536*768*2
  unsigned short* Wt      = (unsigned short*)ws;
  unsigned short* xn      = (unsigned short*)(ws + OFF_XN);
  unsigned short* h2      = xn;                          // reuse after QKV GEMM
  unsigned short* qkv     = (unsigned short*)(ws + OFF_QKV);
  unsigned short* fc1out  = (unsigned short*)(ws + OFF_QKV); // spans qkv+attn regions
  unsigned short* attnout = (unsigned short*)(ws + OFF_ATTN);

  prep_w<<<3072, 256, 0, stream>>>(qkv_w, proj_w, fc1_w, fc2_w, Wt);
  ln1_kernel<<<16384, 256, 0, stream>>>(x, ln1_g, ln1_b, xn);
  gemm_bt<0><<<dim3(6, 512), 256, 0, stream>>>(xn, Wt, qkv, nullptr, nullptr, nullptr, 65536, 768, 256);
  attn_win<<<1024, 256, 0, stream>>>(qkv, rel_tbl, attnout);
  // proj: writes x2 = x + attn_proj + bias directly to d_out (un-permuted)
  gemm_bt<4><<<dim3(2, 512), 256, 0, stream>>>(attnout, Wt + 196608, nullptr, out, proj_b, x, 65536, 256, 256);
  ln2_kernel<<<16384, 256, 0, stream>>>(out, ln2_g, ln2_b, h2);
  gemm_bt<1><<<dim3(8, 512), 256, 0, stream>>>(h2, Wt + 262144, fc1out, nullptr, fc1_b, nullptr, 65536, 1024, 256);
  gemm_bt<3><<<dim3(2, 512), 256, 0, stream>>>(fc1out, Wt + 524288, nullptr, out, fc2_b, nullptr, 65536, 256, 1024);
}

// Round 6
// 424.337 us; speedup vs baseline: 1.2234x; 1.0147x over previous
//
#include <hip/hip_runtime.h>
#include <hip/hip_bf16.h>

typedef __attribute__((ext_vector_type(8))) short bf16x8;
typedef __attribute__((ext_vector_type(4))) float f32x4;

typedef __attribute__((address_space(3))) void LdsVoid;
typedef const __attribute__((address_space(1))) void GblVoid;

__device__ __forceinline__ void gload16(const void* g, void* l) {
  __builtin_amdgcn_global_load_lds((GblVoid*)g, (LdsVoid*)l, 16, 0, 0);
}

__device__ __forceinline__ unsigned short f2bf(float f) {
  union { float f; unsigned int u; } x; x.f = f;
  unsigned int r = (x.u + 0x7fffu + ((x.u >> 16) & 1u)) >> 16;
  return (unsigned short)r;
}

// fast GELU: tanh form, no division (rcp intrinsic), one v_exp_f32.
__device__ __forceinline__ float gelu_f(float t) {
  float u = t * (0.7978845608028654f + 0.03567740814f * t * t);
  float e = __expf(2.0f * u);
  float th = 1.0f - 2.0f * __builtin_amdgcn_rcpf(e + 1.0f);
  return 0.5f * t * (1.0f + th);
}

// ---------------------------------------------------------------- weights prep
// ws layout (ushort elems): qkv_wt[768][256] @0, proj_wt[256][256] @196608,
// fc1_wt[1024][256] @262144, fc2_wt[256][1024] @524288.
__global__ __launch_bounds__(256) void prep_w(
    const float* __restrict__ qw, const float* __restrict__ pw,
    const float* __restrict__ f1, const float* __restrict__ f2,
    unsigned short* __restrict__ out) {
  int idx = blockIdx.x * 256 + threadIdx.x;
  if (idx < 196608) { int n = idx >> 8, k = idx & 255; out[idx] = f2bf(qw[k * 768 + n]); return; }
  int i2 = idx - 196608;
  if (i2 < 65536) { int n = i2 >> 8, k = i2 & 255; out[idx] = f2bf(pw[k * 256 + n]); return; }
  int i3 = i2 - 65536;
  if (i3 < 262144) { int n = i3 >> 8, k = i3 & 255; out[idx] = f2bf(f1[k * 1024 + n]); return; }
  int i4 = i3 - 262144;
  { int n = i4 >> 10, k = i4 & 1023; out[idx] = f2bf(f2[k * 256 + n]); }
}

// ---------------------------------------------------------------- LN1 + window permute
__global__ __launch_bounds__(256) void ln1_kernel(
    const float* __restrict__ x, const float* __restrict__ g, const float* __restrict__ b,
    unsigned short* __restrict__ xn) {
  int lane = threadIdx.x & 63, wid = threadIdx.x >> 6;
  size_t t = (size_t)blockIdx.x * 4 + wid;
  float4 v = ((const float4*)(x + t * 256))[lane];
  float s = v.x + v.y + v.z + v.w;
  #pragma unroll
  for (int m = 1; m < 64; m <<= 1) s += __shfl_xor(s, m);
  float mean = s * (1.0f / 256.0f);
  float dx = v.x - mean, dy = v.y - mean, dz = v.z - mean, dw = v.w - mean;
  float q = dx * dx + dy * dy + dz * dz + dw * dw;
  #pragma unroll
  for (int m = 1; m < 64; m <<= 1) q += __shfl_xor(q, m);
  float rstd = rsqrtf(q * (1.0f / 256.0f) + 1e-5f);
  float4 gg = ((const float4*)g)[lane];
  float4 bb = ((const float4*)b)[lane];
  unsigned int o0 = f2bf(dx * rstd * gg.x + bb.x) | ((unsigned int)f2bf(dy * rstd * gg.y + bb.y) << 16);
  unsigned int o1 = f2bf(dz * rstd * gg.z + bb.z) | ((unsigned int)f2bf(dw * rstd * gg.w + bb.w) << 16);
  int bI = (int)(t >> 12), rem = (int)t & 4095, y = rem >> 6, xc = rem & 63;
  size_t r = ((size_t)(bI * 64 + (y >> 3) * 8 + (xc >> 3))) * 64 + (y & 7) * 8 + (xc & 7);
  uint2 o; o.x = o0; o.y = o1;
  ((uint2*)(xn + r * 256))[lane] = o;
}

// ---------------------------------------------------------------- GEMM: 256x256 8-phase (m201 template port)
// C[M,N] = A[M,K] x Bt[N,K] (both bf16 row-major). BM=BN=256, BK=64 (nkt=K/64),
// 8 waves (2Mx4N), per-wave C = 128x64 as 2x2 quadrant bands of 64x32.
// LDS 128KB: [A|B] x [parity] x [half(128 rows)] of 128x64 bf16, XOR-slot swizzle.
// Per K-tile: 4 phases {reads|stage half-tile; barrier; lgkm0; setprio+16 MFMA; barrier}.
// Stagger: P1->(kt+1).B0, P2->(kt+1).A1, P3->(kt+2).A0, P4->(kt+2).B1; vmcnt(4)
// at K-tile boundary (2 half-tiles in flight), vmcnt(0) for last two boundaries.
// EPI: 0 bf16 out; 1 bf16(gelu(acc+bias)); 3 f32 out += acc+bias;
//      4 f32 out[unpermute(row)] = acc+bias+xres[unpermute(row)]
template <int EPI>
__global__ __launch_bounds__(512, 2) void gemm8p(
    const unsigned short* __restrict__ A, const unsigned short* __restrict__ Bt,
    unsigned short* __restrict__ outb, float* __restrict__ outf,
    const float* __restrict__ bias, const float* __restrict__ xres,
    int M, int N, int K) {
  extern __shared__ unsigned short lds[];
  const int tid = threadIdx.x;
  const int lane = tid & 63, w = tid >> 6;
  const int cl = lane & 15, cg = lane >> 4;
  const int wr = w >> 2, wc = w & 3;  // 2 x 4 waves
  const unsigned nwg = gridDim.x * gridDim.y;
  const unsigned orig = blockIdx.y * gridDim.x + blockIdx.x;
  const unsigned virt = (orig & 7) * (nwg >> 3) + (orig >> 3);
  const unsigned bx = virt % gridDim.x, by = virt / gridDim.x;
  const size_t m0 = (size_t)by * 256, n0 = (size_t)bx * 256;
  const int nkt = K >> 6;

  // staging: thread covers rows trow, trow+64 of a 128-row half; 16B slot tslot.
  // pre-swizzled source: LDS slot s of row r holds logical chunk s^(r&7).
  const int trow = tid >> 3, tslot = tid & 7;
  const unsigned short* aSrc = A + (m0 + trow) * K + (tslot ^ (trow & 7)) * 8;
  const unsigned short* bSrc = Bt + (n0 + trow) * K + (tslot ^ (trow & 7)) * 8;

  // read-side swizzled slot offsets (elems) for kk=0,1 (row&7 == cl&7 for all frag rows)
  const int slk0 = ((0 + cg) ^ (cl & 7)) * 8;
  const int slk1 = ((4 + cg) ^ (cl & 7)) * 8;

  f32x4 acc[8][4] = {};
  bf16x8 af[2][4], b0[2][2], b1[2][2];

  // ISB: 0=A,1=B. dest = [ISB]*32768 + parity*16384 + half*8192 + tid*8 (+4096 j=1)
  #define STAGE(ISB, KT, HALF)                                                    \
    { unsigned short* d_ = lds + (ISB) * 32768 + ((KT) & 1) * 16384 +             \
                           (HALF) * 8192 + tid * 8;                               \
      const unsigned short* s_ = ((ISB) ? bSrc : aSrc) +                          \
                                 (size_t)((HALF) * 128) * K + (KT) * 64;          \
      gload16(s_, d_); gload16(s_ + (size_t)64 * K, d_ + 4096); }

  #define READ_A(MH, P)                                                           \
    { const unsigned short* ba_ = lds + (P) * 16384 + (MH) * 8192 +               \
                                  (wr * 64 + cl) * 64;                            \
      _Pragma("unroll")                                                           \
      for (int mi = 0; mi < 4; ++mi) {                                            \
        af[0][mi] = *(const bf16x8*)(ba_ + mi * 1024 + slk0);                     \
        af[1][mi] = *(const bf16x8*)(ba_ + mi * 1024 + slk1); } }

  #define READ_B(NH, P, D)                                                        \
    { const unsigned short* bb_ = lds + 32768 + (P) * 16384 + (NH) * 8192 +       \
                                  (wc * 32 + cl) * 64;                            \
      _Pragma("unroll")                                                           \
      for (int ni = 0; ni < 2; ++ni) {                                            \
        D[0][ni] = *(const bf16x8*)(bb_ + ni * 1024 + slk0);                      \
        D[1][ni] = *(const bf16x8*)(bb_ + ni * 1024 + slk1); } }

  // swapped operands: C row = A row (lane cl), 4 consecutive C cols per lane
  #define MFMA_Q(MH, NH, D)                                                       \
    { _Pragma("unroll")                                                           \
      for (int kk = 0; kk < 2; ++kk)                                              \
        _Pragma("unroll")                                                         \
        for (int mi = 0; mi < 4; ++mi)                                            \
          _Pragma("unroll")                                                       \
          for (int ni = 0; ni < 2; ++ni)                                          \
            acc[(MH) * 4 + mi][(NH) * 2 + ni] =                                   \
                __builtin_amdgcn_mfma_f32_16x16x32_bf16(                          \
                    D[kk][ni], af[kk][mi], acc[(MH) * 4 + mi][(NH) * 2 + ni],     \
                    0, 0, 0); }

  #define BAR() __builtin_amdgcn_s_barrier()
  #define LGKM0() { asm volatile("s_waitcnt lgkmcnt(0)" ::: "memory");            \
                    __builtin_amdgcn_sched_barrier(0); }

  // prologue: kt0 complete (4 halves) + kt1.{A0,B1}; vmcnt(4) -> kt0 landed
  STAGE(0, 0, 0); STAGE(1, 0, 1); STAGE(1, 0, 0); STAGE(0, 0, 1);
  STAGE(0, 1, 0); STAGE(1, 1, 1);
  asm volatile("s_waitcnt vmcnt(4)" ::: "memory");
  BAR();

  for (int kt = 0; kt < nkt; ++kt) {
    const int p = kt & 1;
    // P1: quadrant (m-half0, n-half0); fresh A0, B0
    READ_A(0, p); READ_B(0, p, b0);
    if (kt + 1 < nkt) STAGE(1, kt + 1, 0);
    BAR(); LGKM0();
    __builtin_amdgcn_s_setprio(1); MFMA_Q(0, 0, b0); __builtin_amdgcn_s_setprio(0);
    BAR();
    // P2: (m0, n1); fresh B1, A0 held
    READ_B(1, p, b1);
    if (kt + 1 < nkt) STAGE(0, kt + 1, 1);
    BAR(); LGKM0();
    __builtin_amdgcn_s_setprio(1); MFMA_Q(0, 1, b1); __builtin_amdgcn_s_setprio(0);
    BAR();
    // P3: (m1, n1); fresh A1, B1 held
    READ_A(1, p);
    if (kt + 2 < nkt) STAGE(0, kt + 2, 0);
    BAR(); LGKM0();
    __builtin_amdgcn_s_setprio(1); MFMA_Q(1, 1, b1); __builtin_amdgcn_s_setprio(0);
    BAR();
    // P4: (m1, n0); A1, B0 held (no reads)
    if (kt + 2 < nkt) STAGE(1, kt + 2, 1);
    BAR();
    __builtin_amdgcn_s_setprio(1); MFMA_Q(1, 0, b0); __builtin_amdgcn_s_setprio(0);
    if (kt + 2 < nkt) { asm volatile("s_waitcnt vmcnt(4)" ::: "memory"); }
    else              { asm volatile("s_waitcnt vmcnt(0)" ::: "memory"); }
    BAR();
  }
  #undef STAGE
  #undef READ_A
  #undef READ_B
  #undef MFMA_Q

  // epilogue: lane cl = row within 16-tile, cg*4..+3 = 4 consecutive cols
  #pragma unroll
  for (int mi8 = 0; mi8 < 8; ++mi8) {
    const size_t row = m0 + (mi8 >> 2) * 128 + wr * 64 + (mi8 & 3) * 16 + cl;
    #pragma unroll
    for (int ni4 = 0; ni4 < 4; ++ni4) {
      const size_t col = n0 + (ni4 >> 1) * 128 + wc * 32 + (ni4 & 1) * 16 + cg * 4;
      f32x4 v = acc[mi8][ni4];
      if (EPI == 0) {
        uint2 o;
        o.x = f2bf(v[0]) | ((unsigned int)f2bf(v[1]) << 16);
        o.y = f2bf(v[2]) | ((unsigned int)f2bf(v[3]) << 16);
        *(uint2*)&outb[row * N + col] = o;
      } else if (EPI == 1) {
        float4 bb = *(const float4*)&bias[col];
        float g0 = gelu_f(v[0] + bb.x), g1 = gelu_f(v[1] + bb.y);
        float g2 = gelu_f(v[2] + bb.z), g3 = gelu_f(v[3] + bb.w);
        uint2 o;
        o.x = f2bf(g0) | ((unsigned int)f2bf(g1) << 16);
        o.y = f2bf(g2) | ((unsigned int)f2bf(g3) << 16);
        *(uint2*)&outb[row * N + col] = o;
      } else if (EPI == 3) {
        float4 bb = *(const float4*)&bias[col];
        float4* pp = (float4*)&outf[row * N + col];
        float4 old = *pp;
        old.x += v[0] + bb.x; old.y += v[1] + bb.y;
        old.z += v[2] + bb.z; old.w += v[3] + bb.w;
        *pp = old;
      } else if (EPI == 4) {
        int winr = (int)(row >> 6), pos = (int)(row & 63);
        int bI = winr >> 6, wy = (winr >> 3) & 7, wx = winr & 7;
        size_t tt = (size_t)bI * 4096 + (size_t)(wy * 8 + (pos >> 3)) * 64 + wx * 8 + (pos & 7);
        float4 bb = *(const float4*)&bias[col];
        float4 xr = *(const float4*)&xres[tt * 256 + col];
        float4 o;
        o.x = v[0] + bb.x + xr.x; o.y = v[1] + bb.y + xr.y;
        o.z = v[2] + bb.z + xr.z; o.w = v[3] + bb.w + xr.w;
        *(float4*)&outf[tt * 256 + col] = o;
      }
    }
  }
}

// ---------------------------------------------------------------- window attention
__global__ __launch_bounds__(256) void attn_win(
    const unsigned short* __restrict__ qkv, const float* __restrict__ table,
    unsigned short* __restrict__ out) {
  __shared__ float tbl[1800];
  __shared__ __align__(16) unsigned short p_lds[4][64 * 72];
  __shared__ __align__(16) unsigned short vt_lds[4][32 * 72];
  const int tid = threadIdx.x, lane = tid & 63, wid = tid >> 6;
  const int cl = lane & 15, cg = lane >> 4;
  for (int i = tid; i < 1800; i += 256) tbl[i] = table[i];
  __syncthreads();
  const size_t wbase = (size_t)blockIdx.x * 64;
  unsigned short* P = p_lds[wid];
  unsigned short* VT = vt_lds[wid];
  const float scale = 0.17677669529663687f;

  for (int hh = 0; hh < 2; ++hh) {
    const int h = wid + hh * 4;
    const int qoff = h * 32, koff = 256 + h * 32, voff = 512 + h * 32;
    bf16x8 qf[4], kf[4];
    #pragma unroll
    for (int mi = 0; mi < 4; ++mi)
      qf[mi] = *(const bf16x8*)&qkv[(wbase + mi * 16 + cl) * 768 + qoff + cg * 8];
    #pragma unroll
    for (int nj = 0; nj < 4; ++nj)
      kf[nj] = *(const bf16x8*)&qkv[(wbase + nj * 16 + cl) * 768 + koff + cg * 8];
    f32x4 S[4][4] = {};
    #pragma unroll
    for (int mi = 0; mi < 4; ++mi)
      #pragma unroll
      for (int nj = 0; nj < 4; ++nj)
        S[mi][nj] = __builtin_amdgcn_mfma_f32_16x16x32_bf16(qf[mi], kf[nj], S[mi][nj], 0, 0, 0);

    {
      const unsigned short* vrow = &qkv[(wbase + lane) * 768 + voff];
      unsigned short tmp[32];
      #pragma unroll
      for (int p = 0; p < 4; ++p) *(uint4*)&tmp[p * 8] = ((const uint4*)vrow)[p];
      #pragma unroll
      for (int d = 0; d < 32; ++d) VT[d * 72 + lane] = tmp[d];
    }

    #pragma unroll
    for (int mi = 0; mi < 4; ++mi) {
      #pragma unroll
      for (int r = 0; r < 4; ++r) {
        const int i = mi * 16 + cg * 4 + r;
        const int yi = i >> 3, xi = i & 7;
        float v[4];
        float m = -1e30f;
        #pragma unroll
        for (int nj = 0; nj < 4; ++nj) {
          const int j = nj * 16 + cl;
          const int yj = j >> 3, xj = j & 7;
          float bia = tbl[((yi - yj + 7) * 15 + (xi - xj + 7)) * 8 + h];
          v[nj] = S[mi][nj][r] * scale + bia;
          m = fmaxf(m, v[nj]);
        }
        #pragma unroll
        for (int mk = 1; mk < 16; mk <<= 1) m = fmaxf(m, __shfl_xor(m, mk));
        float s = 0.0f;
        #pragma unroll
        for (int nj = 0; nj < 4; ++nj) { v[nj] = __expf(v[nj] - m); s += v[nj]; }
        #pragma unroll
        for (int mk = 1; mk < 16; mk <<= 1) s += __shfl_xor(s, mk);
        const float rinv = __builtin_amdgcn_rcpf(s);
        #pragma unroll
        for (int nj = 0; nj < 4; ++nj) P[i * 72 + nj * 16 + cl] = f2bf(v[nj] * rinv);
      }
    }

    f32x4 O[4][2] = {};
    #pragma unroll
    for (int ks = 0; ks < 2; ++ks) {
      bf16x8 pa[4], vb[2];
      #pragma unroll
      for (int mi = 0; mi < 4; ++mi)
        pa[mi] = *(const bf16x8*)&P[(mi * 16 + cl) * 72 + ks * 32 + cg * 8];
      #pragma unroll
      for (int nd = 0; nd < 2; ++nd)
        vb[nd] = *(const bf16x8*)&VT[(nd * 16 + cl) * 72 + ks * 32 + cg * 8];
      #pragma unroll
      for (int mi = 0; mi < 4; ++mi)
        #pragma unroll
        for (int nd = 0; nd < 2; ++nd)
          O[mi][nd] = __builtin_amdgcn_mfma_f32_16x16x32_bf16(vb[nd], pa[mi], O[mi][nd], 0, 0, 0);
    }

    #pragma unroll
    for (int mi = 0; mi < 4; ++mi)
      #pragma unroll
      for (int nd = 0; nd < 2; ++nd) {
        uint2 o;
        o.x = f2bf(O[mi][nd][0]) | ((unsigned int)f2bf(O[mi][nd][1]) << 16);
        o.y = f2bf(O[mi][nd][2]) | ((unsigned int)f2bf(O[mi][nd][3]) << 16);
        *(uint2*)&out[(wbase + mi * 16 + cl) * 256 + h * 32 + nd * 16 + cg * 4] = o;
      }
  }
}

// ---------------------------------------------------------------- LN2 (reads x2 from d_out)
__global__ __launch_bounds__(256) void ln2_kernel(
    const float* __restrict__ x2, const float* __restrict__ g, const float* __restrict__ b,
    unsigned short* __restrict__ h2) {
  int lane = threadIdx.x & 63, wid = threadIdx.x >> 6;
  size_t t = (size_t)blockIdx.x * 4 + wid;
  float4 v = ((const float4*)(x2 + t * 256))[lane];
  float s = v.x + v.y + v.z + v.w;
  #pragma unroll
  for (int m = 1; m < 64; m <<= 1) s += __shfl_xor(s, m);
  float mean = s * (1.0f / 256.0f);
  float dx = v.x - mean, dy = v.y - mean, dz = v.z - mean, dw = v.w - mean;
  float q = dx * dx + dy * dy + dz * dz + dw * dw;
  #pragma unroll
  for (int m = 1; m < 64; m <<= 1) q += __shfl_xor(q, m);
  float rstd = rsqrtf(q * (1.0f / 256.0f) + 1e-5f);
  float4 gg = ((const float4*)g)[lane];
  float4 bb = ((const float4*)b)[lane];
  uint2 o;
  o.x = f2bf(dx * rstd * gg.x + bb.x) | ((unsigned int)f2bf(dy * rstd * gg.y + bb.y) << 16);
  o.y = f2bf(dz * rstd * gg.z + bb.z) | ((unsigned int)f2bf(dw * rstd * gg.w + bb.w) << 16);
  ((uint2*)(h2 + t * 256))[lane] = o;
}

// ---------------------------------------------------------------- launch
extern "C" void kernel_launch(void* const* d_in, const int* in_sizes, int n_in,
                              void* d_out, int out_size, void* d_ws, size_t ws_size,
                              hipStream_t stream) {
  (void)in_sizes; (void)n_in; (void)out_size; (void)ws_size;
  const float* x       = (const float*)d_in[0];
  const float* ln1_g   = (const float*)d_in[3];
  const float* ln1_b   = (const float*)d_in[4];
  const float* qkv_w   = (const float*)d_in[5];
  const float* proj_w  = (const float*)d_in[6];
  const float* proj_b  = (const float*)d_in[7];
  const float* rel_tbl = (const float*)d_in[8];
  const float* ln2_g   = (const float*)d_in[9];
  const float* ln2_b   = (const float*)d_in[10];
  const float* fc1_w   = (const float*)d_in[11];
  const float* fc1_b   = (const float*)d_in[12];
  const float* fc2_w   = (const float*)d_in[13];
  const float* fc2_b   = (const float*)d_in[14];
  float* out = (float*)d_out;

  char* ws = (char*)d_ws;
  const size_t OFF_XN   = 1572864;                 // weights: 786432*2 B
  const size_t OFF_QKV  = OFF_XN + 33554432;       // xn/h2: 65536*256*2
  const size_t OFF_ATTN = OFF_QKV + 100663296;     // qkv: 65536*768*2
  unsigned short* Wt      = (unsigned short*)ws;
  unsigned short* xn      = (unsigned short*)(ws + OFF_XN);
  unsigned short* h2      = xn;                          // reuse after QKV GEMM
  unsigned short* qkv     = (unsigned short*)(ws + OFF_QKV);
  unsigned short* fc1out  = (unsigned short*)(ws + OFF_QKV); // spans qkv+attn regions
  unsigned short* attnout = (unsigned short*)(ws + OFF_ATTN);

  static int attr_done = -1;
  if (attr_done < 0) attr_done = 0;  // no-op; attribute calls are idempotent anyway
  hipFuncSetAttribute((const void*)gemm8p<0>, hipFuncAttributeMaxDynamicSharedMemorySize, 131072);
  hipFuncSetAttribute((const void*)gemm8p<1>, hipFuncAttributeMaxDynamicSharedMemorySize, 131072);
  hipFuncSetAttribute((const void*)gemm8p<3>, hipFuncAttributeMaxDynamicSharedMemorySize, 131072);
  hipFuncSetAttribute((const void*)gemm8p<4>, hipFuncAttributeMaxDynamicSharedMemorySize, 131072);

  prep_w<<<3072, 256, 0, stream>>>(qkv_w, proj_w, fc1_w, fc2_w, Wt);
  ln1_kernel<<<16384, 256, 0, stream>>>(x, ln1_g, ln1_b, xn);
  gemm8p<0><<<dim3(3, 256), 512, 131072, stream>>>(xn, Wt, qkv, nullptr, nullptr, nullptr, 65536, 768, 256);
  attn_win<<<1024, 256, 0, stream>>>(qkv, rel_tbl, attnout);
  // proj: writes x2 = x + attn_proj + bias directly to d_out (un-permuted)
  gemm8p<4><<<dim3(1, 256), 512, 131072, stream>>>(attnout, Wt + 196608, nullptr, out, proj_b, x, 65536, 256, 256);
  ln2_kernel<<<16384, 256, 0, stream>>>(out, ln2_g, ln2_b, h2);
  gemm8p<1><<<dim3(4, 256), 512, 131072, stream>>>(h2, Wt + 262144, fc1out, nullptr, fc1_b, nullptr, 65536, 1024, 256);
  gemm8p<3><<<dim3(1, 256), 512, 131072, stream>>>(fc1out, Wt + 524288, nullptr, out, fc2_b, nullptr, 65536, 256, 1024);
}